// Round 1
// 565.080 us; speedup vs baseline: 1.1345x; 1.1345x over previous
//
#include <hip/hip_runtime.h>
#include <hip/hip_bf16.h>

// Texture_trans: patch-correlation texture transfer + residual conv stack.
// B=4, H=W=64, L=4096, C=64. ALL inputs/outputs fp32. Activations NHWC throughout.
// R13: corr_mfma staging -> global_load_lds from zero-padded pre-split arrays
// (66x66 halo), linear LDS dest + source-side cs-swizzle (cs ^ ((row>>1)&3)) so
// ds_read_b128 stays <=2-way banked. LDS 48K->32K (lval/lidx alias tile space)
// => 4 blocks/CU resident, no tail. Convs unchanged from R12 (verified).
// Workspace: 15,958,016 B. Padded splits alias the conv-buffer region (disjoint life).

#define BATCH 4

typedef unsigned short u16;
typedef unsigned int   u32;
typedef __attribute__((ext_vector_type(8))) short short8;
typedef __attribute__((ext_vector_type(4))) float f32x4;

__device__ __forceinline__ void bsplit2(float a, float b, u32& ho, u32& lo) {
  __hip_bfloat16 ha = __float2bfloat16(a), hb = __float2bfloat16(b);
  float ra = a - __bfloat162float(ha), rb = b - __bfloat162float(hb);
  __hip_bfloat16 la = __float2bfloat16(ra), lb = __float2bfloat16(rb);
  ho = (u32)*(u16*)&ha | ((u32)*(u16*)&hb << 16);
  lo = (u32)*(u16*)&la | ((u32)*(u16*)&lb << 16);
}

__device__ __forceinline__ void gload_lds16(const void* g, void* l) {
  __builtin_amdgcn_global_load_lds((const __attribute__((address_space(1))) void*)g,
                                   (__attribute__((address_space(3))) void*)l, 16, 0, 0);
}

// ---------------- K1: per-pixel channel sum-of-squares from NLC fp32
__global__ __launch_bounds__(256) void prep_ss(const float* __restrict__ c0,
    const float* __restrict__ c1, float* __restrict__ ss0, float* __restrict__ ss1)
{
  int tid = blockIdx.x * 256 + threadIdx.x;
  const float* p0 = c0 + (size_t)tid * 64;
  const float* p1 = c1 + (size_t)tid * 64;
  float s0 = 0.f, s1 = 0.f;
  for (int c = 0; c < 64; ++c) {
    float a = p0[c]; s0 += a * a;
    float b = p1[c]; s1 += b * b;
  }
  ss0[tid] = s0;
  ss1[tid] = s1;
}

// ---------------- K2: 3x3 box-sum of sumsq -> 1/max(patch_norm, EPS)
__global__ __launch_bounds__(256) void norm_kernel(const float* __restrict__ ss0,
    const float* __restrict__ ss1, float* __restrict__ inv0, float* __restrict__ inv1)
{
  int tid = blockIdx.x * 256 + threadIdx.x;
  int b = tid >> 12, l = tid & 4095;
  int y = l >> 6, x = l & 63;
  int base = b << 12;
  float s0 = 0.f, s1 = 0.f;
  for (int dy = -1; dy <= 1; ++dy) {
    int yy = y + dy; if (yy < 0 || yy >= 64) continue;
    for (int dx = -1; dx <= 1; ++dx) {
      int xx = x + dx; if (xx < 0 || xx >= 64) continue;
      int ii = base + (yy << 6) + xx;
      s0 += ss0[ii]; s1 += ss1[ii];
    }
  }
  inv0[tid] = 1.f / fmaxf(sqrtf(s0), 1e-12f);
  inv1[tid] = 1.f / fmaxf(sqrtf(s1), 1e-12f);
}

// ---------------- K3: split fp32 -> bf16 hi + lo into ZERO-PADDED [B][66][66][64]
// halo (border pixels = 0) so corr staging needs no bounds checks and can DMA.
__global__ __launch_bounds__(256) void split_pad_kernel(const float* __restrict__ c0,
    const float* __restrict__ c1, u16* __restrict__ p0h, u16* __restrict__ p0l,
    u16* __restrict__ p1h, u16* __restrict__ p1l)
{
  int b = blockIdx.y, t = threadIdx.x;
  int pix = blockIdx.x * 4 + (t >> 6);   // 0..4355 over 66x66
  int c = t & 63;
  int py = pix / 66, px = pix - py * 66;
  size_t d = ((size_t)b * 4356 + pix) * 64 + c;
  float v0 = 0.f, v1 = 0.f;
  if (py >= 1 && py <= 64 && px >= 1 && px <= 64) {
    size_t s = (((size_t)b << 12) + ((py - 1) << 6) + (px - 1)) * 64 + c;
    v0 = c0[s]; v1 = c1[s];
  }
  __hip_bfloat16 h = __float2bfloat16(v0);
  float r = v0 - __bfloat162float(h);
  __hip_bfloat16 lo = __float2bfloat16(r);
  p0h[d] = *(u16*)&h; p0l[d] = *(u16*)&lo;
  h = __float2bfloat16(v1);
  r = v1 - __bfloat162float(h);
  lo = __float2bfloat16(r);
  p1h[d] = *(u16*)&h; p1l[d] = *(u16*)&lo;
}

// ---------------- K3b: weight transpose+split OIHW fp32 -> [tap][cout][cin] bf16 hi/lo
__global__ __launch_bounds__(256) void wprep(const float* __restrict__ src,
    u16* __restrict__ wh, u16* __restrict__ wl, int Cin, int KK, int n)
{
  int i = blockIdx.x * 256 + threadIdx.x;
  if (i >= n) return;
  int per = Cin * KK;
  int cout = i / per;
  int rem = i - cout * per;
  int cin = rem / KK;
  int tap = rem - cin * KK;
  float x = src[i];
  __hip_bfloat16 h = __float2bfloat16(x);
  float r = x - __bfloat162float(h);
  __hip_bfloat16 lo = __float2bfloat16(r);
  int d = (tap * 64 + cout) * Cin + cin;
  wh[d] = *(u16*)&h;
  wl[d] = *(u16*)&lo;
}

// ---------------- K4: MFMA corr. global_load_lds staging, swizzled chunk layout.
// LDS per matrix: [128 rows][4 slots][8 u16], linear; slot s of row r holds data
// chunk cs = s ^ ((r>>1)&3). Wave w stages matrix w (0:A_hi 1:A_lo 2:B_hi 3:B_lo).
__global__ __launch_bounds__(256) void corr_mfma(const u16* __restrict__ p0h,
    const u16* __restrict__ p0l, const u16* __restrict__ p1h, const u16* __restrict__ p1l,
    const float* __restrict__ inv0, float* __restrict__ pval, int* __restrict__ pidx)
{
  __shared__ __align__(16) u16 smem[16384];   // 32 KB: 4 matrices x 4096 u16
  int mt = blockIdx.x, lt = blockIdx.y, b = blockIdx.z;
  int t = threadIdx.x;
  int lane = t & 63, w = t >> 6;
  int wl = w >> 1, wm = w & 1;
  int cc = lane & 15, q = lane >> 4;
  const size_t boff = (size_t)b * 278784;     // 66*66*64
  const u16* msrc = (w == 0) ? p0h : (w == 1) ? p0l : (w == 2) ? p1h : p1l;
  msrc += boff;
  const float* inv0b = inv0 + (b << 12);
  u16* ldsm = smem + (w << 12);               // 4096 u16 per matrix
  int isB = w >> 1;

  // staging lane constants: lanes 4k..4k+3 cover cs slots 0..3 of one row
  int srow0 = lane >> 2;                      // row within 16-row chunk
  int cs_g  = (lane & 3) ^ ((lane >> 3) & 3); // source chunk for this lane's slot
  int sw    = (cc >> 1) & 3;                  // read-side swizzle key

  float bval[4] = {-1e30f, -1e30f, -1e30f, -1e30f};
  int   bidx[4] = {0, 0, 0, 0};

  for (int sub = 0; sub < 4; ++sub) {
    int row0 = (lt << 9) + (sub << 7);
    int pb = isB ? (mt << 7) : row0;          // base pixel index for my matrix
    f32x4 acc[4][4];
#pragma unroll
    for (int i = 0; i < 4; ++i)
#pragma unroll
      for (int j = 0; j < 4; ++j) acc[i][j] = (f32x4){0.f, 0.f, 0.f, 0.f};

    for (int ph = 0; ph < 18; ++ph) {
      int r = ph >> 1, hh = ph & 1;
      int ki = r / 3, kj = r - ki * 3;        // padded offsets: +ki, +kj (halo = +1)
      __syncthreads();
#pragma unroll
      for (int it = 0; it < 8; ++it) {
        int row = (it << 4) + srow0;
        int p = pb + row;
        int ypad = (p >> 6) + ki, xpad = (p & 63) + kj;
        const u16* g = msrc + (((size_t)(ypad * 66 + xpad)) << 6) + (hh << 5) + (cs_g << 3);
        gload_lds16(g, ldsm + (it << 9));     // wave-uniform dst, +lane*16B by HW
      }
      __syncthreads();
      short8 afh[4], afl[4], bfh[4], bfl[4];
#pragma unroll
      for (int i = 0; i < 4; ++i) {
        int ra = (((wl << 6) + (i << 4) + cc) << 5) + ((q ^ sw) << 3);
        afh[i] = *(const short8*)(&smem[ra]);
        afl[i] = *(const short8*)(&smem[4096 + ra]);
      }
#pragma unroll
      for (int j = 0; j < 4; ++j) {
        int rb = (((wm << 6) + (j << 4) + cc) << 5) + ((q ^ sw) << 3);
        bfh[j] = *(const short8*)(&smem[8192 + rb]);
        bfl[j] = *(const short8*)(&smem[12288 + rb]);
      }
#pragma unroll
      for (int i = 0; i < 4; ++i)
#pragma unroll
        for (int j = 0; j < 4; ++j) {
          acc[i][j] = __builtin_amdgcn_mfma_f32_16x16x32_bf16(afh[i], bfl[j], acc[i][j], 0, 0, 0);
          acc[i][j] = __builtin_amdgcn_mfma_f32_16x16x32_bf16(afl[i], bfh[j], acc[i][j], 0, 0, 0);
          acc[i][j] = __builtin_amdgcn_mfma_f32_16x16x32_bf16(afh[i], bfh[j], acc[i][j], 0, 0, 0);
        }
    }
#pragma unroll
    for (int i = 0; i < 4; ++i) {
#pragma unroll
      for (int rg = 0; rg < 4; ++rg) {
        int l = row0 + (wl << 6) + (i << 4) + (q << 2) + rg;
        float sc = inv0b[l];
#pragma unroll
        for (int j = 0; j < 4; ++j) {
          float v = acc[i][j][rg] * sc;
          if (v > bval[j]) { bval[j] = v; bidx[j] = l; }
        }
      }
    }
  }

  __syncthreads();                            // tiles dead; alias reduce buffers
  float* lval = (float*)smem;                 // 4096 B
  int*   lidx = (int*)((char*)smem + 4096);   // 4096 B
  int slot = (wl << 2) + q;
#pragma unroll
  for (int j = 0; j < 4; ++j) {
    int col = (wm << 6) + (j << 4) + cc;
    lval[col * 8 + slot] = bval[j];
    lidx[col * 8 + slot] = bidx[j];
  }
  __syncthreads();
  if (t < 128) {
    float bv = -1e30f; int bi = 0x7FFFFFFF;
    for (int s = 0; s < 8; ++s) {
      float v = lval[t * 8 + s]; int id = lidx[t * 8 + s];
      if (v > bv || (v == bv && id < bi)) { bv = v; bi = id; }
    }
    size_t o = (size_t)(((b << 3) + lt) << 12) + (mt << 7) + t;
    pval[o] = bv; pidx[o] = bi;
  }
}

// ---------------- K5: reduce partials -> S, argmax
__global__ __launch_bounds__(256) void reduce_kernel(const float* __restrict__ pval,
    const int* __restrict__ pidx, const float* __restrict__ inv1,
    float* __restrict__ S, int* __restrict__ arg)
{
  int tid = blockIdx.x * 256 + threadIdx.x;
  int b = tid >> 12, m = tid & 4095;
  float bv = -1e30f; int bi = 0x7FFFFFFF;
  for (int lt = 0; lt < 8; ++lt) {
    size_t o = (size_t)(((b << 3) + lt) << 12) + m;
    float v = pval[o]; int id = pidx[o];
    if (v > bv || (v == bv && id < bi)) { bv = v; bi = id; }
  }
  S[tid] = bv * inv1[tid];
  arg[tid] = ((unsigned)bi < 4096u) ? bi : 0;
}

// ---------------- K6: T = fold3(gather(f0_unfold, arg))/9 -> NHWC fp32
__global__ __launch_bounds__(256) void tgather_kernel(const float* __restrict__ f0,
    const int* __restrict__ arg, float* __restrict__ T)
{
  __shared__ int a3[192];
  int y = blockIdx.x, b = blockIdx.y, t = threadIdx.x;
  if (t < 192) {
    int r = t >> 6, xx = t & 63;
    int yy = y + r - 1;
    a3[t] = (yy >= 0 && yy < 64) ? arg[(b << 12) + (yy << 6) + xx] : 0;
  }
  __syncthreads();
  int c = t & 63, pg = t >> 6;
  for (int it = 0; it < 16; ++it) {
    int px = pg + (it << 2);
    float sum = 0.f;
#pragma unroll
    for (int ki = 0; ki < 3; ++ki) {
      int yn = y + 1 - ki;
      if (yn < 0 || yn >= 64) continue;
#pragma unroll
      for (int kj = 0; kj < 3; ++kj) {
        int xn = px + 1 - kj;
        if (xn < 0 || xn >= 64) continue;
        int p = a3[((2 - ki) << 6) + xn];
        int sy = (p >> 6) + ki - 1, sx = (p & 63) + kj - 1;
        if (sy >= 0 && sy < 64 && sx >= 0 && sx < 64)
          sum += f0[((((size_t)b << 12) + (sy << 6) + sx) << 6) + c];
      }
    }
    T[((((size_t)b << 12) + (y << 6) + px)) * 64 + c] = sum * (1.f / 9.f);
  }
}

// ---------------- K7: implicit-GEMM MFMA conv, NHWC fp32 act, pre-split bf16 weights.
template<int KS, int CINCH>
__global__ __launch_bounds__(256) void conv_mfma(const float* __restrict__ in0,
    const float* __restrict__ in1, const u16* __restrict__ whp, const u16* __restrict__ wlp,
    const float* __restrict__ bias, float* __restrict__ outp,
    const float* __restrict__ res, int dorelu, int dm)
{
  constexpr int P = KS / 2;
  constexpr int CIN = CINCH * 32;
  __shared__ __align__(16) u16 Ah[64 * 40], Al[64 * 40];
  __shared__ __align__(16) u16 Bh[64 * 40], Bl[64 * 40];
  int tile = blockIdx.x, b = blockIdx.y;       // tile = image row y
  int t = threadIdx.x;
  int lane = t & 63, w = t >> 6;
  int wh2 = w >> 1, wm = w & 1;
  int cc = lane & 15, q = lane >> 4;
  const size_t abase = (size_t)b << 12;
  f32x4 acc[2][2];
#pragma unroll
  for (int i = 0; i < 2; ++i)
#pragma unroll
    for (int j = 0; j < 2; ++j) acc[i][j] = (f32x4){0.f, 0.f, 0.f, 0.f};

  for (int tap = 0; tap < KS * KS; ++tap) {
    int ki = tap / KS, kj = tap - ki * KS;
    int iy = tile + ki - P;
    for (int kk = 0; kk < CINCH; ++kk) {
      __syncthreads();
      {  // stage A: 64 rows x 32 cin, hi/lo; 256 items (1/thread)
        int row = t >> 2, cs = t & 3;
        int ix = row + kj - P;
        float v[8];
#pragma unroll
        for (int e = 0; e < 8; ++e) v[e] = 0.f;
        if ((unsigned)iy < 64u && (unsigned)ix < 64u) {
          size_t base = (abase + (iy << 6) + ix) << 6;
          int cg = kk * 32 + (cs << 3);
          if (dm) {
            float4 a0 = *(const float4*)(in0 + base + cg);
            float4 a1 = *(const float4*)(in0 + base + cg + 4);
            float4 b0 = *(const float4*)(in1 + base + cg);
            float4 b1 = *(const float4*)(in1 + base + cg + 4);
            v[0] = b0.x - a0.x; v[1] = b0.y - a0.y; v[2] = b0.z - a0.z; v[3] = b0.w - a0.w;
            v[4] = b1.x - a1.x; v[5] = b1.y - a1.y; v[6] = b1.z - a1.z; v[7] = b1.w - a1.w;
          } else {
            const float* sp = (CINCH == 4 && cg >= 64) ? (in1 + base + (cg - 64))
                                                       : (in0 + base + cg);
            float4 a0 = *(const float4*)sp;
            float4 a1 = *(const float4*)(sp + 4);
            v[0] = a0.x; v[1] = a0.y; v[2] = a0.z; v[3] = a0.w;
            v[4] = a1.x; v[5] = a1.y; v[6] = a1.z; v[7] = a1.w;
          }
        }
        uint4 uh, ul;
        bsplit2(v[0], v[1], uh.x, ul.x);
        bsplit2(v[2], v[3], uh.y, ul.y);
        bsplit2(v[4], v[5], uh.z, ul.z);
        bsplit2(v[6], v[7], uh.w, ul.w);
        *(uint4*)&Ah[row * 40 + (cs << 3)] = uh;
        *(uint4*)&Al[row * 40 + (cs << 3)] = ul;
      }
#pragma unroll
      for (int it = 0; it < 2; ++it) {  // stage B: 64 couts x 32 cin, h then l
        int row = t >> 2, cs = t & 3;
        const u16* wsrc = it ? wlp : whp;
        uint4 vv = *(const uint4*)&wsrc[(size_t)(tap * 64 + row) * CIN + kk * 32 + (cs << 3)];
        u16* dst = it ? Bl : Bh;
        *(uint4*)&dst[row * 40 + (cs << 3)] = vv;
      }
      __syncthreads();
      short8 afh[2], afl[2], bfh[2], bfl[2];
#pragma unroll
      for (int i = 0; i < 2; ++i) {
        int ra = ((wh2 << 5) + (i << 4) + cc) * 40 + (q << 3);
        afh[i] = *(const short8*)&Ah[ra];
        afl[i] = *(const short8*)&Al[ra];
      }
#pragma unroll
      for (int j = 0; j < 2; ++j) {
        int rb = ((wm << 5) + (j << 4) + cc) * 40 + (q << 3);
        bfh[j] = *(const short8*)&Bh[rb];
        bfl[j] = *(const short8*)&Bl[rb];
      }
#pragma unroll
      for (int i = 0; i < 2; ++i)
#pragma unroll
        for (int j = 0; j < 2; ++j) {
          acc[i][j] = __builtin_amdgcn_mfma_f32_16x16x32_bf16(afh[i], bfl[j], acc[i][j], 0, 0, 0);
          acc[i][j] = __builtin_amdgcn_mfma_f32_16x16x32_bf16(afl[i], bfh[j], acc[i][j], 0, 0, 0);
          acc[i][j] = __builtin_amdgcn_mfma_f32_16x16x32_bf16(afh[i], bfh[j], acc[i][j], 0, 0, 0);
        }
    }
  }
#pragma unroll
  for (int i = 0; i < 2; ++i)
#pragma unroll
    for (int rg = 0; rg < 4; ++rg) {
      int p = (tile << 6) + (wh2 << 5) + (i << 4) + (q << 2) + rg;
#pragma unroll
      for (int j = 0; j < 2; ++j) {
        int cout = (wm << 5) + (j << 4) + cc;
        float v = acc[i][j][rg] + bias[cout];
        if (dorelu) v = fmaxf(v, 0.f);
        size_t oi = ((abase + p) << 6) + cout;
        if (res) v += res[oi];
        outp[oi] = v;
      }
    }
}

// ---------------- K8: out = dcf + xs*S
__global__ __launch_bounds__(256) void final_kernel(const float* __restrict__ dcf,
    const float* __restrict__ xs, const float* __restrict__ S, float* __restrict__ out)
{
  int tid = blockIdx.x * 256 + threadIdx.x;
  out[tid] = dcf[tid] + xs[tid] * S[tid >> 6];
}

extern "C" void kernel_launch(void* const* d_in, const int* in_sizes, int n_in,
                              void* d_out, int out_size, void* d_ws, size_t ws_size,
                              hipStream_t stream)
{
  (void)in_sizes; (void)n_in; (void)out_size; (void)ws_size;
  const float* c0     = (const float*)d_in[0];
  const float* f0     = (const float*)d_in[1];
  const float* c1     = (const float*)d_in[2];
  const float* head_w = (const float*)d_in[3];
  const float* head_b = (const float*)d_in[4];
  const float* rb_w1  = (const float*)d_in[5];
  const float* rb_b1  = (const float*)d_in[6];
  const float* rb_w2  = (const float*)d_in[7];
  const float* rb_b2  = (const float*)d_in[8];
  const float* tail_w = (const float*)d_in[9];
  const float* tail_b = (const float*)d_in[10];
  const float* sq_w   = (const float*)d_in[11];
  const float* sq_b   = (const float*)d_in[12];
  float* out = (float*)d_out;
  char* ws = (char*)d_ws;

  // ---- layout: 15,958,016 B total ----
  const size_t OFF_SS0  = 0;
  const size_t OFF_SS1  = 65536;
  const size_t OFF_INV0 = 131072;
  const size_t OFF_INV1 = 196608;
  const size_t OFF_S    = 262144;
  const size_t OFF_ARG  = 327680;
  const size_t OFF_PVAL = 393216;       // 512 KB
  const size_t OFF_PIDX = 917504;       // 512 KB
  const size_t OFF_WHH  = 1441792;      // head  hi 204800
  const size_t OFF_WHL  = 1646592;      // head  lo 204800
  const size_t OFF_W1H  = 1851392;      // rb1   hi 73728
  const size_t OFF_W1L  = 1925120;
  const size_t OFF_W2H  = 1998848;      // rb2   hi 73728
  const size_t OFF_W2L  = 2072576;
  const size_t OFF_WTH  = 2146304;      // tail  hi 204800
  const size_t OFF_WTL  = 2351104;
  const size_t OFF_WSH  = 2555904;      // sq    hi 409600
  const size_t OFF_WSL  = 2965504;
  // big region 3,375,104 .. 15,958,016 (12 MiB), two disjoint lifetimes:
  //  (1) corr phase: padded splits p0h/p0l/p1h/p1l, 4 x 2,230,272 = 8,921,088 B
  //  (2) conv phase: SA/SB/SC 4 MiB slots (x1/T | hb/dcf | xb/xs)
  const size_t OFF_P0H  = 3375104;
  const size_t OFF_P0L  = OFF_P0H + 2230272;   // 5,605,376
  const size_t OFF_P1H  = OFF_P0L + 2230272;   // 7,835,648
  const size_t OFF_P1L  = OFF_P1H + 2230272;   // 10,065,920 (end 12,296,192)
  const size_t OFF_SA   = 3375104;      // 4 MB: x1 -> T
  const size_t OFF_SB   = 7569408;      // 4 MB: hb -> dcf
  const size_t OFF_SC   = 11763712;     // 4 MB: xb -> xs

  float* ss0  = (float*)(ws + OFF_SS0);
  float* ss1  = (float*)(ws + OFF_SS1);
  float* inv0 = (float*)(ws + OFF_INV0);
  float* inv1 = (float*)(ws + OFF_INV1);
  float* Sbuf = (float*)(ws + OFF_S);
  int*   argb = (int*)(ws + OFF_ARG);
  float* pval = (float*)(ws + OFF_PVAL);
  int*   pidx = (int*)(ws + OFF_PIDX);
  u16* whh = (u16*)(ws + OFF_WHH); u16* whl = (u16*)(ws + OFF_WHL);
  u16* w1h = (u16*)(ws + OFF_W1H); u16* w1l = (u16*)(ws + OFF_W1L);
  u16* w2h = (u16*)(ws + OFF_W2H); u16* w2l = (u16*)(ws + OFF_W2L);
  u16* wth = (u16*)(ws + OFF_WTH); u16* wtl = (u16*)(ws + OFF_WTL);
  u16* wsh = (u16*)(ws + OFF_WSH); u16* wsl = (u16*)(ws + OFF_WSL);
  u16* p0h = (u16*)(ws + OFF_P0H); u16* p0l = (u16*)(ws + OFF_P0L);
  u16* p1h = (u16*)(ws + OFF_P1H); u16* p1l = (u16*)(ws + OFF_P1L);
  float* x1  = (float*)(ws + OFF_SA);
  float* Tb  = (float*)(ws + OFF_SA);
  float* hb  = (float*)(ws + OFF_SB);
  float* dcf = (float*)(ws + OFF_SB);
  float* xb  = (float*)(ws + OFF_SC);
  float* xsb = (float*)(ws + OFF_SC);

  dim3 b256(256);
  prep_ss<<<dim3(64), b256, 0, stream>>>(c0, c1, ss0, ss1);
  norm_kernel<<<dim3(64), b256, 0, stream>>>(ss0, ss1, inv0, inv1);
  split_pad_kernel<<<dim3(1089, BATCH), b256, 0, stream>>>(c0, c1, p0h, p0l, p1h, p1l);
  wprep<<<dim3(400), b256, 0, stream>>>(head_w, whh, whl, 64, 25, 102400);
  wprep<<<dim3(144), b256, 0, stream>>>(rb_w1 + 110592, w1h, w1l, 64, 9, 36864);
  wprep<<<dim3(144), b256, 0, stream>>>(rb_w2 + 110592, w2h, w2l, 64, 9, 36864);
  wprep<<<dim3(400), b256, 0, stream>>>(tail_w, wth, wtl, 64, 25, 102400);
  wprep<<<dim3(800), b256, 0, stream>>>(sq_w, wsh, wsl, 128, 25, 204800);

  corr_mfma<<<dim3(32, 8, BATCH), b256, 0, stream>>>(p0h, p0l, p1h, p1l, inv0, pval, pidx);
  reduce_kernel<<<dim3(64), b256, 0, stream>>>(pval, pidx, inv1, Sbuf, argb);

  // conv stack (only residual block 3 affects output); all NHWC.
  // Stream-ordered: these overwrite the padded-split region, which is dead now.
  dim3 cgrid(64, BATCH);
  conv_mfma<5, 2><<<cgrid, b256, 0, stream>>>(c0, c1, whh, whl, head_b, x1, nullptr, 0, 1);
  conv_mfma<3, 2><<<cgrid, b256, 0, stream>>>(x1, nullptr, w1h, w1l, rb_b1 + 192, hb, nullptr, 1, 0);
  conv_mfma<3, 2><<<cgrid, b256, 0, stream>>>(hb, nullptr, w2h, w2l, rb_b2 + 192, xb, x1, 0, 0);
  conv_mfma<5, 2><<<cgrid, b256, 0, stream>>>(xb, nullptr, wth, wtl, tail_b, dcf, x1, 0, 0);

  tgather_kernel<<<dim3(64, BATCH), b256, 0, stream>>>(f0, argb, Tb);   // x1 dead after conv4
  conv_mfma<5, 4><<<cgrid, b256, 0, stream>>>(dcf, Tb, wsh, wsl, sq_b, xsb, nullptr, 0, 0);

  final_kernel<<<dim3(4096), b256, 0, stream>>>(dcf, xsb, Sbuf, out);
}

// Round 2
// 555.331 us; speedup vs baseline: 1.1544x; 1.0176x over previous
//
#include <hip/hip_runtime.h>
#include <hip/hip_bf16.h>

// Texture_trans: patch-correlation texture transfer + residual conv stack.
// B=4, H=W=64, L=4096, C=64. ALL inputs/outputs fp32. Activations NHWC throughout.
// R14: (a) corr_mfma -> T3/T4 minimum-2-phase pipeline: double-buffered 2x32KB LDS,
// prefetch next phase's global_load_lds before computing current, counted
// s_waitcnt vmcnt(8) + raw s_barrier (no full drain in the main loop).
// (b) conv_mfma -> 32-px tiles (grid 128xB, 2 blocks/CU) with split staging duty:
// waves 0-1 stage A (bsplit), waves 2-3 stage B concurrently. Fragment math
// unchanged from verified R12/R13 pattern.
// Workspace: 15,958,016 B, layout unchanged from R13.

#define BATCH 4

typedef unsigned short u16;
typedef unsigned int   u32;
typedef __attribute__((ext_vector_type(8))) short short8;
typedef __attribute__((ext_vector_type(4))) float f32x4;

__device__ __forceinline__ void bsplit2(float a, float b, u32& ho, u32& lo) {
  __hip_bfloat16 ha = __float2bfloat16(a), hb = __float2bfloat16(b);
  float ra = a - __bfloat162float(ha), rb = b - __bfloat162float(hb);
  __hip_bfloat16 la = __float2bfloat16(ra), lb = __float2bfloat16(rb);
  ho = (u32)*(u16*)&ha | ((u32)*(u16*)&hb << 16);
  lo = (u32)*(u16*)&la | ((u32)*(u16*)&lb << 16);
}

__device__ __forceinline__ void gload_lds16(const void* g, void* l) {
  __builtin_amdgcn_global_load_lds((const __attribute__((address_space(1))) void*)g,
                                   (__attribute__((address_space(3))) void*)l, 16, 0, 0);
}

// ---------------- K1: per-pixel channel sum-of-squares from NLC fp32
__global__ __launch_bounds__(256) void prep_ss(const float* __restrict__ c0,
    const float* __restrict__ c1, float* __restrict__ ss0, float* __restrict__ ss1)
{
  int tid = blockIdx.x * 256 + threadIdx.x;
  const float* p0 = c0 + (size_t)tid * 64;
  const float* p1 = c1 + (size_t)tid * 64;
  float s0 = 0.f, s1 = 0.f;
  for (int c = 0; c < 64; ++c) {
    float a = p0[c]; s0 += a * a;
    float b = p1[c]; s1 += b * b;
  }
  ss0[tid] = s0;
  ss1[tid] = s1;
}

// ---------------- K2: 3x3 box-sum of sumsq -> 1/max(patch_norm, EPS)
__global__ __launch_bounds__(256) void norm_kernel(const float* __restrict__ ss0,
    const float* __restrict__ ss1, float* __restrict__ inv0, float* __restrict__ inv1)
{
  int tid = blockIdx.x * 256 + threadIdx.x;
  int b = tid >> 12, l = tid & 4095;
  int y = l >> 6, x = l & 63;
  int base = b << 12;
  float s0 = 0.f, s1 = 0.f;
  for (int dy = -1; dy <= 1; ++dy) {
    int yy = y + dy; if (yy < 0 || yy >= 64) continue;
    for (int dx = -1; dx <= 1; ++dx) {
      int xx = x + dx; if (xx < 0 || xx >= 64) continue;
      int ii = base + (yy << 6) + xx;
      s0 += ss0[ii]; s1 += ss1[ii];
    }
  }
  inv0[tid] = 1.f / fmaxf(sqrtf(s0), 1e-12f);
  inv1[tid] = 1.f / fmaxf(sqrtf(s1), 1e-12f);
}

// ---------------- K3: split fp32 -> bf16 hi + lo into ZERO-PADDED [B][66][66][64]
__global__ __launch_bounds__(256) void split_pad_kernel(const float* __restrict__ c0,
    const float* __restrict__ c1, u16* __restrict__ p0h, u16* __restrict__ p0l,
    u16* __restrict__ p1h, u16* __restrict__ p1l)
{
  int b = blockIdx.y, t = threadIdx.x;
  int pix = blockIdx.x * 4 + (t >> 6);   // 0..4355 over 66x66
  int c = t & 63;
  int py = pix / 66, px = pix - py * 66;
  size_t d = ((size_t)b * 4356 + pix) * 64 + c;
  float v0 = 0.f, v1 = 0.f;
  if (py >= 1 && py <= 64 && px >= 1 && px <= 64) {
    size_t s = (((size_t)b << 12) + ((py - 1) << 6) + (px - 1)) * 64 + c;
    v0 = c0[s]; v1 = c1[s];
  }
  __hip_bfloat16 h = __float2bfloat16(v0);
  float r = v0 - __bfloat162float(h);
  __hip_bfloat16 lo = __float2bfloat16(r);
  p0h[d] = *(u16*)&h; p0l[d] = *(u16*)&lo;
  h = __float2bfloat16(v1);
  r = v1 - __bfloat162float(h);
  lo = __float2bfloat16(r);
  p1h[d] = *(u16*)&h; p1l[d] = *(u16*)&lo;
}

// ---------------- K3b: weight transpose+split OIHW fp32 -> [tap][cout][cin] bf16 hi/lo
__global__ __launch_bounds__(256) void wprep(const float* __restrict__ src,
    u16* __restrict__ wh, u16* __restrict__ wl, int Cin, int KK, int n)
{
  int i = blockIdx.x * 256 + threadIdx.x;
  if (i >= n) return;
  int per = Cin * KK;
  int cout = i / per;
  int rem = i - cout * per;
  int cin = rem / KK;
  int tap = rem - cin * KK;
  float x = src[i];
  __hip_bfloat16 h = __float2bfloat16(x);
  float r = x - __bfloat162float(h);
  __hip_bfloat16 lo = __float2bfloat16(r);
  int d = (tap * 64 + cout) * Cin + cin;
  wh[d] = *(u16*)&h;
  wl[d] = *(u16*)&lo;
}

// ---------------- K4: MFMA corr. Double-buffered DMA pipeline (T3/T4-min).
// LDS: 2 buffers x 4 matrices x 4096 u16 (swizzled chunk layout, slot s of row r
// holds chunk s ^ ((r>>1)&3)). Wave w stages matrix w. Counted vmcnt(8): next
// phase's 8 loads stay in flight across the barrier; never drain in-loop.
__global__ __launch_bounds__(256) void corr_mfma(const u16* __restrict__ p0h,
    const u16* __restrict__ p0l, const u16* __restrict__ p1h, const u16* __restrict__ p1l,
    const float* __restrict__ inv0, float* __restrict__ pval, int* __restrict__ pidx)
{
  __shared__ __align__(16) u16 smem[32768];   // 64 KB: 2 x (4 matrices x 4096)
  int mt = blockIdx.x, lt = blockIdx.y, b = blockIdx.z;
  int t = threadIdx.x;
  int lane = t & 63, w = t >> 6;
  int wl = w >> 1, wm = w & 1;
  int cc = lane & 15, q = lane >> 4;
  const size_t boff = (size_t)b * 278784;     // 66*66*64
  const u16* msrc = (w == 0) ? p0h : (w == 1) ? p0l : (w == 2) ? p1h : p1l;
  msrc += boff;
  const float* inv0b = inv0 + (b << 12);
  int isB = w >> 1;

  int srow0 = lane >> 2;                      // row within 16-row chunk
  int cs_g  = (lane & 3) ^ ((lane >> 3) & 3); // source chunk for this lane's slot
  int sw    = (cc >> 1) & 3;                  // read-side swizzle key

  // issue one phase's 8 DMA loads for (ssub, sph) into LDS buffer base dst
  auto stage = [&](int ssub, int sph, u16* dst) {
    int r = sph >> 1, hh = sph & 1;
    int ki = r / 3, kj = r - ki * 3;
    int pb = isB ? (mt << 7) : ((lt << 9) + (ssub << 7));
#pragma unroll
    for (int it = 0; it < 8; ++it) {
      int p = pb + (it << 4) + srow0;
      int ypad = (p >> 6) + ki, xpad = (p & 63) + kj;
      const u16* g = msrc + (((size_t)(ypad * 66 + xpad)) << 6) + (hh << 5) + (cs_g << 3);
      gload_lds16(g, dst + (it << 9));
    }
  };

  float bval[4] = {-1e30f, -1e30f, -1e30f, -1e30f};
  int   bidx[4] = {0, 0, 0, 0};

  // prologue: stage phase g=0 into buffer 0
  stage(0, 0, smem + (w << 12));

  for (int sub = 0; sub < 4; ++sub) {
    int row0 = (lt << 9) + (sub << 7);
    f32x4 acc[4][4];
#pragma unroll
    for (int i = 0; i < 4; ++i)
#pragma unroll
      for (int j = 0; j < 4; ++j) acc[i][j] = (f32x4){0.f, 0.f, 0.f, 0.f};

    for (int ph = 0; ph < 18; ++ph) {
      int g = sub * 18 + ph;
      int nxt = g + 1;
      if (nxt < 72) {
        int np = ph + 1, ns = sub;
        if (np == 18) { np = 0; ++ns; }
        stage(ns, np, smem + ((nxt & 1) << 14) + (w << 12));
        asm volatile("s_waitcnt vmcnt(8)" ::: "memory");   // phase g landed; g+1 in flight
      } else {
        asm volatile("s_waitcnt vmcnt(0)" ::: "memory");
      }
      __builtin_amdgcn_s_barrier();
      __builtin_amdgcn_sched_barrier(0);
      const u16* bb = smem + ((g & 1) << 14);
      short8 afh[4], afl[4], bfh[4], bfl[4];
#pragma unroll
      for (int i = 0; i < 4; ++i) {
        int ra = (((wl << 6) + (i << 4) + cc) << 5) + ((q ^ sw) << 3);
        afh[i] = *(const short8*)(&bb[ra]);
        afl[i] = *(const short8*)(&bb[4096 + ra]);
      }
#pragma unroll
      for (int j = 0; j < 4; ++j) {
        int rb = (((wm << 6) + (j << 4) + cc) << 5) + ((q ^ sw) << 3);
        bfh[j] = *(const short8*)(&bb[8192 + rb]);
        bfl[j] = *(const short8*)(&bb[12288 + rb]);
      }
#pragma unroll
      for (int i = 0; i < 4; ++i)
#pragma unroll
        for (int j = 0; j < 4; ++j) {
          acc[i][j] = __builtin_amdgcn_mfma_f32_16x16x32_bf16(afh[i], bfl[j], acc[i][j], 0, 0, 0);
          acc[i][j] = __builtin_amdgcn_mfma_f32_16x16x32_bf16(afl[i], bfh[j], acc[i][j], 0, 0, 0);
          acc[i][j] = __builtin_amdgcn_mfma_f32_16x16x32_bf16(afh[i], bfh[j], acc[i][j], 0, 0, 0);
        }
      __builtin_amdgcn_sched_barrier(0);
      __builtin_amdgcn_s_barrier();          // readers done before buf re-staged
    }
#pragma unroll
    for (int i = 0; i < 4; ++i) {
#pragma unroll
      for (int rg = 0; rg < 4; ++rg) {
        int l = row0 + (wl << 6) + (i << 4) + (q << 2) + rg;
        float sc = inv0b[l];
#pragma unroll
        for (int j = 0; j < 4; ++j) {
          float v = acc[i][j][rg] * sc;
          if (v > bval[j]) { bval[j] = v; bidx[j] = l; }
        }
      }
    }
  }

  __syncthreads();                            // tiles dead; alias reduce buffers
  float* lval = (float*)smem;                 // 4096 B
  int*   lidx = (int*)((char*)smem + 4096);   // 4096 B
  int slot = (wl << 2) + q;
#pragma unroll
  for (int j = 0; j < 4; ++j) {
    int col = (wm << 6) + (j << 4) + cc;
    lval[col * 8 + slot] = bval[j];
    lidx[col * 8 + slot] = bidx[j];
  }
  __syncthreads();
  if (t < 128) {
    float bv = -1e30f; int bi = 0x7FFFFFFF;
    for (int s = 0; s < 8; ++s) {
      float v = lval[t * 8 + s]; int id = lidx[t * 8 + s];
      if (v > bv || (v == bv && id < bi)) { bv = v; bi = id; }
    }
    size_t o = (size_t)(((b << 3) + lt) << 12) + (mt << 7) + t;
    pval[o] = bv; pidx[o] = bi;
  }
}

// ---------------- K5: reduce partials -> S, argmax
__global__ __launch_bounds__(256) void reduce_kernel(const float* __restrict__ pval,
    const int* __restrict__ pidx, const float* __restrict__ inv1,
    float* __restrict__ S, int* __restrict__ arg)
{
  int tid = blockIdx.x * 256 + threadIdx.x;
  int b = tid >> 12, m = tid & 4095;
  float bv = -1e30f; int bi = 0x7FFFFFFF;
  for (int lt = 0; lt < 8; ++lt) {
    size_t o = (size_t)(((b << 3) + lt) << 12) + m;
    float v = pval[o]; int id = pidx[o];
    if (v > bv || (v == bv && id < bi)) { bv = v; bi = id; }
  }
  S[tid] = bv * inv1[tid];
  arg[tid] = ((unsigned)bi < 4096u) ? bi : 0;
}

// ---------------- K6: T = fold3(gather(f0_unfold, arg))/9 -> NHWC fp32
__global__ __launch_bounds__(256) void tgather_kernel(const float* __restrict__ f0,
    const int* __restrict__ arg, float* __restrict__ T)
{
  __shared__ int a3[192];
  int y = blockIdx.x, b = blockIdx.y, t = threadIdx.x;
  if (t < 192) {
    int r = t >> 6, xx = t & 63;
    int yy = y + r - 1;
    a3[t] = (yy >= 0 && yy < 64) ? arg[(b << 12) + (yy << 6) + xx] : 0;
  }
  __syncthreads();
  int c = t & 63, pg = t >> 6;
  for (int it = 0; it < 16; ++it) {
    int px = pg + (it << 2);
    float sum = 0.f;
#pragma unroll
    for (int ki = 0; ki < 3; ++ki) {
      int yn = y + 1 - ki;
      if (yn < 0 || yn >= 64) continue;
#pragma unroll
      for (int kj = 0; kj < 3; ++kj) {
        int xn = px + 1 - kj;
        if (xn < 0 || xn >= 64) continue;
        int p = a3[((2 - ki) << 6) + xn];
        int sy = (p >> 6) + ki - 1, sx = (p & 63) + kj - 1;
        if (sy >= 0 && sy < 64 && sx >= 0 && sx < 64)
          sum += f0[((((size_t)b << 12) + (sy << 6) + sx) << 6) + c];
      }
    }
    T[((((size_t)b << 12) + (y << 6) + px)) * 64 + c] = sum * (1.f / 9.f);
  }
}

// ---------------- K7: implicit-GEMM MFMA conv, NHWC fp32 act, pre-split bf16 weights.
// R14: tile = 32 px x 64 cout; grid (128, B) -> 2 blocks/CU. Waves: wpx = px half
// (16), wm = cout half (32). Staging split: threads <128 stage A (load+bsplit),
// threads >=128 stage B (weights), concurrently.
template<int KS, int CINCH>
__global__ __launch_bounds__(256) void conv_mfma(const float* __restrict__ in0,
    const float* __restrict__ in1, const u16* __restrict__ whp, const u16* __restrict__ wlp,
    const float* __restrict__ bias, float* __restrict__ outp,
    const float* __restrict__ res, int dorelu, int dm)
{
  constexpr int P = KS / 2;
  constexpr int CIN = CINCH * 32;
  __shared__ __align__(16) u16 Ah[32 * 40], Al[32 * 40];
  __shared__ __align__(16) u16 Bh[64 * 40], Bl[64 * 40];
  int tile = blockIdx.x, b = blockIdx.y;       // tile: y = tile>>1, px half = tile&1
  int t = threadIdx.x;
  int lane = t & 63, w = t >> 6;
  int wpx = w >> 1, wm = w & 1;
  int cc = lane & 15, q = lane >> 4;
  int ty = tile >> 1, txb = (tile & 1) << 5;
  const size_t abase = (size_t)b << 12;
  f32x4 acc[2];
#pragma unroll
  for (int j = 0; j < 2; ++j) acc[j] = (f32x4){0.f, 0.f, 0.f, 0.f};

  for (int tap = 0; tap < KS * KS; ++tap) {
    int ki = tap / KS, kj = tap - ki * KS;
    int iy = ty + ki - P;
    for (int kk = 0; kk < CINCH; ++kk) {
      __syncthreads();
      if (t < 128) {  // stage A: 32 rows x 32 cin, hi/lo
        int row = t >> 2, cs = t & 3;
        int ix = txb + row + kj - P;
        float v[8];
#pragma unroll
        for (int e = 0; e < 8; ++e) v[e] = 0.f;
        if ((unsigned)iy < 64u && (unsigned)ix < 64u) {
          size_t base = (abase + (iy << 6) + ix) << 6;
          int cg = kk * 32 + (cs << 3);
          if (dm) {
            float4 a0 = *(const float4*)(in0 + base + cg);
            float4 a1 = *(const float4*)(in0 + base + cg + 4);
            float4 b0 = *(const float4*)(in1 + base + cg);
            float4 b1 = *(const float4*)(in1 + base + cg + 4);
            v[0] = b0.x - a0.x; v[1] = b0.y - a0.y; v[2] = b0.z - a0.z; v[3] = b0.w - a0.w;
            v[4] = b1.x - a1.x; v[5] = b1.y - a1.y; v[6] = b1.z - a1.z; v[7] = b1.w - a1.w;
          } else {
            const float* sp = (CINCH == 4 && cg >= 64) ? (in1 + base + (cg - 64))
                                                       : (in0 + base + cg);
            float4 a0 = *(const float4*)sp;
            float4 a1 = *(const float4*)(sp + 4);
            v[0] = a0.x; v[1] = a0.y; v[2] = a0.z; v[3] = a0.w;
            v[4] = a1.x; v[5] = a1.y; v[6] = a1.z; v[7] = a1.w;
          }
        }
        uint4 uh, ul;
        bsplit2(v[0], v[1], uh.x, ul.x);
        bsplit2(v[2], v[3], uh.y, ul.y);
        bsplit2(v[4], v[5], uh.z, ul.z);
        bsplit2(v[6], v[7], uh.w, ul.w);
        *(uint4*)&Ah[row * 40 + (cs << 3)] = uh;
        *(uint4*)&Al[row * 40 + (cs << 3)] = ul;
      } else {        // stage B: 64 couts x 32 cin, hi+lo (2 chunks each per thread)
        int tb = t - 128;
#pragma unroll
        for (int rr = 0; rr < 2; ++rr) {
          int idx = tb * 2 + rr;               // 0..255
          int cout = idx >> 2, cs = idx & 3;
          size_t so = (size_t)(tap * 64 + cout) * CIN + kk * 32 + (cs << 3);
          uint4 vh = *(const uint4*)&whp[so];
          uint4 vl = *(const uint4*)&wlp[so];
          *(uint4*)&Bh[cout * 40 + (cs << 3)] = vh;
          *(uint4*)&Bl[cout * 40 + (cs << 3)] = vl;
        }
      }
      __syncthreads();
      short8 afh, afl, bfh[2], bfl[2];
      {
        int ra = ((wpx << 4) + cc) * 40 + (q << 3);
        afh = *(const short8*)&Ah[ra];
        afl = *(const short8*)&Al[ra];
      }
#pragma unroll
      for (int j = 0; j < 2; ++j) {
        int rb = ((wm << 5) + (j << 4) + cc) * 40 + (q << 3);
        bfh[j] = *(const short8*)&Bh[rb];
        bfl[j] = *(const short8*)&Bl[rb];
      }
#pragma unroll
      for (int j = 0; j < 2; ++j) {
        acc[j] = __builtin_amdgcn_mfma_f32_16x16x32_bf16(afh, bfl[j], acc[j], 0, 0, 0);
        acc[j] = __builtin_amdgcn_mfma_f32_16x16x32_bf16(afl, bfh[j], acc[j], 0, 0, 0);
        acc[j] = __builtin_amdgcn_mfma_f32_16x16x32_bf16(afh, bfh[j], acc[j], 0, 0, 0);
      }
    }
  }
#pragma unroll
  for (int rg = 0; rg < 4; ++rg) {
    int p = (ty << 6) + txb + (wpx << 4) + (q << 2) + rg;
#pragma unroll
    for (int j = 0; j < 2; ++j) {
      int cout = (wm << 5) + (j << 4) + cc;
      float v = acc[j][rg] + bias[cout];
      if (dorelu) v = fmaxf(v, 0.f);
      size_t oi = ((abase + p) << 6) + cout;
      if (res) v += res[oi];
      outp[oi] = v;
    }
  }
}

// ---------------- K8: out = dcf + xs*S
__global__ __launch_bounds__(256) void final_kernel(const float* __restrict__ dcf,
    const float* __restrict__ xs, const float* __restrict__ S, float* __restrict__ out)
{
  int tid = blockIdx.x * 256 + threadIdx.x;
  out[tid] = dcf[tid] + xs[tid] * S[tid >> 6];
}

extern "C" void kernel_launch(void* const* d_in, const int* in_sizes, int n_in,
                              void* d_out, int out_size, void* d_ws, size_t ws_size,
                              hipStream_t stream)
{
  (void)in_sizes; (void)n_in; (void)out_size; (void)ws_size;
  const float* c0     = (const float*)d_in[0];
  const float* f0     = (const float*)d_in[1];
  const float* c1     = (const float*)d_in[2];
  const float* head_w = (const float*)d_in[3];
  const float* head_b = (const float*)d_in[4];
  const float* rb_w1  = (const float*)d_in[5];
  const float* rb_b1  = (const float*)d_in[6];
  const float* rb_w2  = (const float*)d_in[7];
  const float* rb_b2  = (const float*)d_in[8];
  const float* tail_w = (const float*)d_in[9];
  const float* tail_b = (const float*)d_in[10];
  const float* sq_w   = (const float*)d_in[11];
  const float* sq_b   = (const float*)d_in[12];
  float* out = (float*)d_out;
  char* ws = (char*)d_ws;

  // ---- layout: 15,958,016 B total (unchanged from R13) ----
  const size_t OFF_SS0  = 0;
  const size_t OFF_SS1  = 65536;
  const size_t OFF_INV0 = 131072;
  const size_t OFF_INV1 = 196608;
  const size_t OFF_S    = 262144;
  const size_t OFF_ARG  = 327680;
  const size_t OFF_PVAL = 393216;       // 512 KB
  const size_t OFF_PIDX = 917504;       // 512 KB
  const size_t OFF_WHH  = 1441792;      // head  hi 204800
  const size_t OFF_WHL  = 1646592;      // head  lo 204800
  const size_t OFF_W1H  = 1851392;      // rb1   hi 73728
  const size_t OFF_W1L  = 1925120;
  const size_t OFF_W2H  = 1998848;      // rb2   hi 73728
  const size_t OFF_W2L  = 2072576;
  const size_t OFF_WTH  = 2146304;      // tail  hi 204800
  const size_t OFF_WTL  = 2351104;
  const size_t OFF_WSH  = 2555904;      // sq    hi 409600
  const size_t OFF_WSL  = 2965504;
  const size_t OFF_P0H  = 3375104;
  const size_t OFF_P0L  = OFF_P0H + 2230272;   // 5,605,376
  const size_t OFF_P1H  = OFF_P0L + 2230272;   // 7,835,648
  const size_t OFF_P1L  = OFF_P1H + 2230272;   // 10,065,920 (end 12,296,192)
  const size_t OFF_SA   = 3375104;      // 4 MB: x1 -> T
  const size_t OFF_SB   = 7569408;      // 4 MB: hb -> dcf
  const size_t OFF_SC   = 11763712;     // 4 MB: xb -> xs

  float* ss0  = (float*)(ws + OFF_SS0);
  float* ss1  = (float*)(ws + OFF_SS1);
  float* inv0 = (float*)(ws + OFF_INV0);
  float* inv1 = (float*)(ws + OFF_INV1);
  float* Sbuf = (float*)(ws + OFF_S);
  int*   argb = (int*)(ws + OFF_ARG);
  float* pval = (float*)(ws + OFF_PVAL);
  int*   pidx = (int*)(ws + OFF_PIDX);
  u16* whh = (u16*)(ws + OFF_WHH); u16* whl = (u16*)(ws + OFF_WHL);
  u16* w1h = (u16*)(ws + OFF_W1H); u16* w1l = (u16*)(ws + OFF_W1L);
  u16* w2h = (u16*)(ws + OFF_W2H); u16* w2l = (u16*)(ws + OFF_W2L);
  u16* wth = (u16*)(ws + OFF_WTH); u16* wtl = (u16*)(ws + OFF_WTL);
  u16* wsh = (u16*)(ws + OFF_WSH); u16* wsl = (u16*)(ws + OFF_WSL);
  u16* p0h = (u16*)(ws + OFF_P0H); u16* p0l = (u16*)(ws + OFF_P0L);
  u16* p1h = (u16*)(ws + OFF_P1H); u16* p1l = (u16*)(ws + OFF_P1L);
  float* x1  = (float*)(ws + OFF_SA);
  float* Tb  = (float*)(ws + OFF_SA);
  float* hb  = (float*)(ws + OFF_SB);
  float* dcf = (float*)(ws + OFF_SB);
  float* xb  = (float*)(ws + OFF_SC);
  float* xsb = (float*)(ws + OFF_SC);

  dim3 b256(256);
  prep_ss<<<dim3(64), b256, 0, stream>>>(c0, c1, ss0, ss1);
  norm_kernel<<<dim3(64), b256, 0, stream>>>(ss0, ss1, inv0, inv1);
  split_pad_kernel<<<dim3(1089, BATCH), b256, 0, stream>>>(c0, c1, p0h, p0l, p1h, p1l);
  wprep<<<dim3(400), b256, 0, stream>>>(head_w, whh, whl, 64, 25, 102400);
  wprep<<<dim3(144), b256, 0, stream>>>(rb_w1 + 110592, w1h, w1l, 64, 9, 36864);
  wprep<<<dim3(144), b256, 0, stream>>>(rb_w2 + 110592, w2h, w2l, 64, 9, 36864);
  wprep<<<dim3(400), b256, 0, stream>>>(tail_w, wth, wtl, 64, 25, 102400);
  wprep<<<dim3(800), b256, 0, stream>>>(sq_w, wsh, wsl, 128, 25, 204800);

  corr_mfma<<<dim3(32, 8, BATCH), b256, 0, stream>>>(p0h, p0l, p1h, p1l, inv0, pval, pidx);
  reduce_kernel<<<dim3(64), b256, 0, stream>>>(pval, pidx, inv1, Sbuf, argb);

  // conv stack (only residual block 3 affects output); all NHWC.
  // Stream-ordered: these overwrite the padded-split region, which is dead now.
  dim3 cgrid(128, BATCH);
  conv_mfma<5, 2><<<cgrid, b256, 0, stream>>>(c0, c1, whh, whl, head_b, x1, nullptr, 0, 1);
  conv_mfma<3, 2><<<cgrid, b256, 0, stream>>>(x1, nullptr, w1h, w1l, rb_b1 + 192, hb, nullptr, 1, 0);
  conv_mfma<3, 2><<<cgrid, b256, 0, stream>>>(hb, nullptr, w2h, w2l, rb_b2 + 192, xb, x1, 0, 0);
  conv_mfma<5, 2><<<cgrid, b256, 0, stream>>>(xb, nullptr, wth, wtl, tail_b, dcf, x1, 0, 0);

  tgather_kernel<<<dim3(64, BATCH), b256, 0, stream>>>(f0, argb, Tb);   // x1 dead after conv4
  conv_mfma<5, 4><<<cgrid, b256, 0, stream>>>(dcf, Tb, wsh, wsl, sq_b, xsb, nullptr, 0, 0);

  final_kernel<<<dim3(4096), b256, 0, stream>>>(dcf, xsb, Sbuf, out);
}

// Round 3
// 529.355 us; speedup vs baseline: 1.2110x; 1.0491x over previous
//
#include <hip/hip_runtime.h>
#include <hip/hip_bf16.h>

// Texture_trans: patch-correlation texture transfer + residual conv stack.
// B=4, H=W=64, L=4096, C=64. ALL inputs/outputs fp32. Activations NHWC throughout.
// R15: conv_mfma -> reg-staged single-barrier pipeline (T14): issue iter n+1's
// global loads into regs after writing iter n's LDS, then lgkmcnt(0)+s_barrier
// (vmcnt NOT drained -> loads in flight across the barrier), double-buffered
// 2x15KB LDS, ONE barrier per (tap,kk) iteration. Fragment math/epilogue
// byte-identical to verified R14. corr_mfma and all other kernels unchanged.
// Workspace: 15,958,016 B, layout unchanged.

#define BATCH 4

typedef unsigned short u16;
typedef unsigned int   u32;
typedef __attribute__((ext_vector_type(8))) short short8;
typedef __attribute__((ext_vector_type(4))) float f32x4;

__device__ __forceinline__ void bsplit2(float a, float b, u32& ho, u32& lo) {
  __hip_bfloat16 ha = __float2bfloat16(a), hb = __float2bfloat16(b);
  float ra = a - __bfloat162float(ha), rb = b - __bfloat162float(hb);
  __hip_bfloat16 la = __float2bfloat16(ra), lb = __float2bfloat16(rb);
  ho = (u32)*(u16*)&ha | ((u32)*(u16*)&hb << 16);
  lo = (u32)*(u16*)&la | ((u32)*(u16*)&lb << 16);
}

__device__ __forceinline__ void gload_lds16(const void* g, void* l) {
  __builtin_amdgcn_global_load_lds((const __attribute__((address_space(1))) void*)g,
                                   (__attribute__((address_space(3))) void*)l, 16, 0, 0);
}

// ---------------- K1: per-pixel channel sum-of-squares from NLC fp32
__global__ __launch_bounds__(256) void prep_ss(const float* __restrict__ c0,
    const float* __restrict__ c1, float* __restrict__ ss0, float* __restrict__ ss1)
{
  int tid = blockIdx.x * 256 + threadIdx.x;
  const float* p0 = c0 + (size_t)tid * 64;
  const float* p1 = c1 + (size_t)tid * 64;
  float s0 = 0.f, s1 = 0.f;
  for (int c = 0; c < 64; ++c) {
    float a = p0[c]; s0 += a * a;
    float b = p1[c]; s1 += b * b;
  }
  ss0[tid] = s0;
  ss1[tid] = s1;
}

// ---------------- K2: 3x3 box-sum of sumsq -> 1/max(patch_norm, EPS)
__global__ __launch_bounds__(256) void norm_kernel(const float* __restrict__ ss0,
    const float* __restrict__ ss1, float* __restrict__ inv0, float* __restrict__ inv1)
{
  int tid = blockIdx.x * 256 + threadIdx.x;
  int b = tid >> 12, l = tid & 4095;
  int y = l >> 6, x = l & 63;
  int base = b << 12;
  float s0 = 0.f, s1 = 0.f;
  for (int dy = -1; dy <= 1; ++dy) {
    int yy = y + dy; if (yy < 0 || yy >= 64) continue;
    for (int dx = -1; dx <= 1; ++dx) {
      int xx = x + dx; if (xx < 0 || xx >= 64) continue;
      int ii = base + (yy << 6) + xx;
      s0 += ss0[ii]; s1 += ss1[ii];
    }
  }
  inv0[tid] = 1.f / fmaxf(sqrtf(s0), 1e-12f);
  inv1[tid] = 1.f / fmaxf(sqrtf(s1), 1e-12f);
}

// ---------------- K3: split fp32 -> bf16 hi + lo into ZERO-PADDED [B][66][66][64]
__global__ __launch_bounds__(256) void split_pad_kernel(const float* __restrict__ c0,
    const float* __restrict__ c1, u16* __restrict__ p0h, u16* __restrict__ p0l,
    u16* __restrict__ p1h, u16* __restrict__ p1l)
{
  int b = blockIdx.y, t = threadIdx.x;
  int pix = blockIdx.x * 4 + (t >> 6);   // 0..4355 over 66x66
  int c = t & 63;
  int py = pix / 66, px = pix - py * 66;
  size_t d = ((size_t)b * 4356 + pix) * 64 + c;
  float v0 = 0.f, v1 = 0.f;
  if (py >= 1 && py <= 64 && px >= 1 && px <= 64) {
    size_t s = (((size_t)b << 12) + ((py - 1) << 6) + (px - 1)) * 64 + c;
    v0 = c0[s]; v1 = c1[s];
  }
  __hip_bfloat16 h = __float2bfloat16(v0);
  float r = v0 - __bfloat162float(h);
  __hip_bfloat16 lo = __float2bfloat16(r);
  p0h[d] = *(u16*)&h; p0l[d] = *(u16*)&lo;
  h = __float2bfloat16(v1);
  r = v1 - __bfloat162float(h);
  lo = __float2bfloat16(r);
  p1h[d] = *(u16*)&h; p1l[d] = *(u16*)&lo;
}

// ---------------- K3b: weight transpose+split OIHW fp32 -> [tap][cout][cin] bf16 hi/lo
__global__ __launch_bounds__(256) void wprep(const float* __restrict__ src,
    u16* __restrict__ wh, u16* __restrict__ wl, int Cin, int KK, int n)
{
  int i = blockIdx.x * 256 + threadIdx.x;
  if (i >= n) return;
  int per = Cin * KK;
  int cout = i / per;
  int rem = i - cout * per;
  int cin = rem / KK;
  int tap = rem - cin * KK;
  float x = src[i];
  __hip_bfloat16 h = __float2bfloat16(x);
  float r = x - __bfloat162float(h);
  __hip_bfloat16 lo = __float2bfloat16(r);
  int d = (tap * 64 + cout) * Cin + cin;
  wh[d] = *(u16*)&h;
  wl[d] = *(u16*)&lo;
}

// ---------------- K4: MFMA corr. Double-buffered DMA pipeline (unchanged R14).
__global__ __launch_bounds__(256) void corr_mfma(const u16* __restrict__ p0h,
    const u16* __restrict__ p0l, const u16* __restrict__ p1h, const u16* __restrict__ p1l,
    const float* __restrict__ inv0, float* __restrict__ pval, int* __restrict__ pidx)
{
  __shared__ __align__(16) u16 smem[32768];   // 64 KB: 2 x (4 matrices x 4096)
  int mt = blockIdx.x, lt = blockIdx.y, b = blockIdx.z;
  int t = threadIdx.x;
  int lane = t & 63, w = t >> 6;
  int wl = w >> 1, wm = w & 1;
  int cc = lane & 15, q = lane >> 4;
  const size_t boff = (size_t)b * 278784;     // 66*66*64
  const u16* msrc = (w == 0) ? p0h : (w == 1) ? p0l : (w == 2) ? p1h : p1l;
  msrc += boff;
  const float* inv0b = inv0 + (b << 12);
  int isB = w >> 1;

  int srow0 = lane >> 2;                      // row within 16-row chunk
  int cs_g  = (lane & 3) ^ ((lane >> 3) & 3); // source chunk for this lane's slot
  int sw    = (cc >> 1) & 3;                  // read-side swizzle key

  auto stage = [&](int ssub, int sph, u16* dst) {
    int r = sph >> 1, hh = sph & 1;
    int ki = r / 3, kj = r - ki * 3;
    int pb = isB ? (mt << 7) : ((lt << 9) + (ssub << 7));
#pragma unroll
    for (int it = 0; it < 8; ++it) {
      int p = pb + (it << 4) + srow0;
      int ypad = (p >> 6) + ki, xpad = (p & 63) + kj;
      const u16* g = msrc + (((size_t)(ypad * 66 + xpad)) << 6) + (hh << 5) + (cs_g << 3);
      gload_lds16(g, dst + (it << 9));
    }
  };

  float bval[4] = {-1e30f, -1e30f, -1e30f, -1e30f};
  int   bidx[4] = {0, 0, 0, 0};

  stage(0, 0, smem + (w << 12));

  for (int sub = 0; sub < 4; ++sub) {
    int row0 = (lt << 9) + (sub << 7);
    f32x4 acc[4][4];
#pragma unroll
    for (int i = 0; i < 4; ++i)
#pragma unroll
      for (int j = 0; j < 4; ++j) acc[i][j] = (f32x4){0.f, 0.f, 0.f, 0.f};

    for (int ph = 0; ph < 18; ++ph) {
      int g = sub * 18 + ph;
      int nxt = g + 1;
      if (nxt < 72) {
        int np = ph + 1, ns = sub;
        if (np == 18) { np = 0; ++ns; }
        stage(ns, np, smem + ((nxt & 1) << 14) + (w << 12));
        asm volatile("s_waitcnt vmcnt(8)" ::: "memory");   // phase g landed; g+1 in flight
      } else {
        asm volatile("s_waitcnt vmcnt(0)" ::: "memory");
      }
      __builtin_amdgcn_s_barrier();
      __builtin_amdgcn_sched_barrier(0);
      const u16* bb = smem + ((g & 1) << 14);
      short8 afh[4], afl[4], bfh[4], bfl[4];
#pragma unroll
      for (int i = 0; i < 4; ++i) {
        int ra = (((wl << 6) + (i << 4) + cc) << 5) + ((q ^ sw) << 3);
        afh[i] = *(const short8*)(&bb[ra]);
        afl[i] = *(const short8*)(&bb[4096 + ra]);
      }
#pragma unroll
      for (int j = 0; j < 4; ++j) {
        int rb = (((wm << 6) + (j << 4) + cc) << 5) + ((q ^ sw) << 3);
        bfh[j] = *(const short8*)(&bb[8192 + rb]);
        bfl[j] = *(const short8*)(&bb[12288 + rb]);
      }
#pragma unroll
      for (int i = 0; i < 4; ++i)
#pragma unroll
        for (int j = 0; j < 4; ++j) {
          acc[i][j] = __builtin_amdgcn_mfma_f32_16x16x32_bf16(afh[i], bfl[j], acc[i][j], 0, 0, 0);
          acc[i][j] = __builtin_amdgcn_mfma_f32_16x16x32_bf16(afl[i], bfh[j], acc[i][j], 0, 0, 0);
          acc[i][j] = __builtin_amdgcn_mfma_f32_16x16x32_bf16(afh[i], bfh[j], acc[i][j], 0, 0, 0);
        }
      __builtin_amdgcn_sched_barrier(0);
      __builtin_amdgcn_s_barrier();          // readers done before buf re-staged
    }
#pragma unroll
    for (int i = 0; i < 4; ++i) {
#pragma unroll
      for (int rg = 0; rg < 4; ++rg) {
        int l = row0 + (wl << 6) + (i << 4) + (q << 2) + rg;
        float sc = inv0b[l];
#pragma unroll
        for (int j = 0; j < 4; ++j) {
          float v = acc[i][j][rg] * sc;
          if (v > bval[j]) { bval[j] = v; bidx[j] = l; }
        }
      }
    }
  }

  __syncthreads();                            // tiles dead; alias reduce buffers
  float* lval = (float*)smem;                 // 4096 B
  int*   lidx = (int*)((char*)smem + 4096);   // 4096 B
  int slot = (wl << 2) + q;
#pragma unroll
  for (int j = 0; j < 4; ++j) {
    int col = (wm << 6) + (j << 4) + cc;
    lval[col * 8 + slot] = bval[j];
    lidx[col * 8 + slot] = bidx[j];
  }
  __syncthreads();
  if (t < 128) {
    float bv = -1e30f; int bi = 0x7FFFFFFF;
    for (int s = 0; s < 8; ++s) {
      float v = lval[t * 8 + s]; int id = lidx[t * 8 + s];
      if (v > bv || (v == bv && id < bi)) { bv = v; bi = id; }
    }
    size_t o = (size_t)(((b << 3) + lt) << 12) + (mt << 7) + t;
    pval[o] = bv; pidx[o] = bi;
  }
}

// ---------------- K5: reduce partials -> S, argmax
__global__ __launch_bounds__(256) void reduce_kernel(const float* __restrict__ pval,
    const int* __restrict__ pidx, const float* __restrict__ inv1,
    float* __restrict__ S, int* __restrict__ arg)
{
  int tid = blockIdx.x * 256 + threadIdx.x;
  int b = tid >> 12, m = tid & 4095;
  float bv = -1e30f; int bi = 0x7FFFFFFF;
  for (int lt = 0; lt < 8; ++lt) {
    size_t o = (size_t)(((b << 3) + lt) << 12) + m;
    float v = pval[o]; int id = pidx[o];
    if (v > bv || (v == bv && id < bi)) { bv = v; bi = id; }
  }
  S[tid] = bv * inv1[tid];
  arg[tid] = ((unsigned)bi < 4096u) ? bi : 0;
}

// ---------------- K6: T = fold3(gather(f0_unfold, arg))/9 -> NHWC fp32
__global__ __launch_bounds__(256) void tgather_kernel(const float* __restrict__ f0,
    const int* __restrict__ arg, float* __restrict__ T)
{
  __shared__ int a3[192];
  int y = blockIdx.x, b = blockIdx.y, t = threadIdx.x;
  if (t < 192) {
    int r = t >> 6, xx = t & 63;
    int yy = y + r - 1;
    a3[t] = (yy >= 0 && yy < 64) ? arg[(b << 12) + (yy << 6) + xx] : 0;
  }
  __syncthreads();
  int c = t & 63, pg = t >> 6;
  for (int it = 0; it < 16; ++it) {
    int px = pg + (it << 2);
    float sum = 0.f;
#pragma unroll
    for (int ki = 0; ki < 3; ++ki) {
      int yn = y + 1 - ki;
      if (yn < 0 || yn >= 64) continue;
#pragma unroll
      for (int kj = 0; kj < 3; ++kj) {
        int xn = px + 1 - kj;
        if (xn < 0 || xn >= 64) continue;
        int p = a3[((2 - ki) << 6) + xn];
        int sy = (p >> 6) + ki - 1, sx = (p & 63) + kj - 1;
        if (sy >= 0 && sy < 64 && sx >= 0 && sx < 64)
          sum += f0[((((size_t)b << 12) + (sy << 6) + sx) << 6) + c];
      }
    }
    T[((((size_t)b << 12) + (y << 6) + px)) * 64 + c] = sum * (1.f / 9.f);
  }
}

// ---------------- K7: implicit-GEMM MFMA conv, NHWC fp32 act, pre-split bf16 weights.
// R15: reg-staged single-barrier pipeline. Tile = 32 px x 64 cout; grid (128, B).
// Per (tap,kk) iteration: write LDS[cur] from regs -> issue next iter's global
// loads into regs -> lgkmcnt(0) + s_barrier (vmcnt NOT drained) -> ds_read + MFMA.
// Double-buffered LDS (2x15KB). Fragment math identical to verified R14.
template<int KS, int CINCH>
__global__ __launch_bounds__(256) void conv_mfma(const float* __restrict__ in0,
    const float* __restrict__ in1, const u16* __restrict__ whp, const u16* __restrict__ wlp,
    const float* __restrict__ bias, float* __restrict__ outp,
    const float* __restrict__ res, int dorelu, int dm)
{
  constexpr int P = KS / 2;
  constexpr int CIN = CINCH * 32;
  constexpr int KSH = (CINCH == 2) ? 1 : 2;
  constexpr int NIT = KS * KS * CINCH;
  __shared__ __align__(16) u16 Ah[2][32 * 40], Al[2][32 * 40];
  __shared__ __align__(16) u16 Bh[2][64 * 40], Bl[2][64 * 40];
  int tile = blockIdx.x, b = blockIdx.y;       // tile: y = tile>>1, px half = tile&1
  int t = threadIdx.x;
  int lane = t & 63, w = t >> 6;
  int wpx = w >> 1, wm = w & 1;
  int cc = lane & 15, q = lane >> 4;
  int ty = tile >> 1, txb = (tile & 1) << 5;
  const size_t abase = (size_t)b << 12;
  f32x4 acc[2];
  acc[0] = (f32x4){0.f, 0.f, 0.f, 0.f};
  acc[1] = (f32x4){0.f, 0.f, 0.f, 0.f};

  uint4 rg[4];                                 // staging regs (A: act data, B: weights)
  int arow = t >> 2, acs = t & 3;              // A-thread mapping (t < 128)
  int tb = t - 128;                            // B-thread index (t >= 128)

  auto issue_loads = [&](int itn) {
    int tapn = itn >> KSH, kkn = itn & (CINCH - 1);
    int ki = tapn / KS, kj = tapn - ki * KS;
    if (t < 128) {
      rg[0] = rg[1] = rg[2] = rg[3] = make_uint4(0u, 0u, 0u, 0u);
      int iy = ty + ki - P;
      int ix = txb + arow + kj - P;
      if ((unsigned)iy < 64u && (unsigned)ix < 64u) {
        size_t base = (abase + (iy << 6) + ix) << 6;
        int cg = kkn * 32 + (acs << 3);
        if (dm) {
          rg[0] = *(const uint4*)(in0 + base + cg);
          rg[1] = *(const uint4*)(in0 + base + cg + 4);
          rg[2] = *(const uint4*)(in1 + base + cg);
          rg[3] = *(const uint4*)(in1 + base + cg + 4);
        } else {
          const float* sp = (CINCH == 4 && cg >= 64) ? (in1 + base + (cg - 64))
                                                     : (in0 + base + cg);
          rg[0] = *(const uint4*)sp;
          rg[1] = *(const uint4*)(sp + 4);
        }
      }
    } else {
#pragma unroll
      for (int rr = 0; rr < 2; ++rr) {
        int idx = tb * 2 + rr;                 // 0..255
        int cout = idx >> 2, cs = idx & 3;
        size_t so = (size_t)(tapn * 64 + cout) * CIN + kkn * 32 + (cs << 3);
        rg[rr]     = *(const uint4*)&whp[so];
        rg[2 + rr] = *(const uint4*)&wlp[so];
      }
    }
  };

  auto write_lds = [&](int cur) {
    if (t < 128) {
      float v[8];
      if (dm) {
#pragma unroll
        for (int e = 0; e < 4; ++e) {
          v[e]     = __uint_as_float((&rg[2].x)[e]) - __uint_as_float((&rg[0].x)[e]);
          v[4 + e] = __uint_as_float((&rg[3].x)[e]) - __uint_as_float((&rg[1].x)[e]);
        }
      } else {
#pragma unroll
        for (int e = 0; e < 4; ++e) {
          v[e]     = __uint_as_float((&rg[0].x)[e]);
          v[4 + e] = __uint_as_float((&rg[1].x)[e]);
        }
      }
      uint4 uh, ul;
      bsplit2(v[0], v[1], uh.x, ul.x);
      bsplit2(v[2], v[3], uh.y, ul.y);
      bsplit2(v[4], v[5], uh.z, ul.z);
      bsplit2(v[6], v[7], uh.w, ul.w);
      *(uint4*)&Ah[cur][arow * 40 + (acs << 3)] = uh;
      *(uint4*)&Al[cur][arow * 40 + (acs << 3)] = ul;
    } else {
#pragma unroll
      for (int rr = 0; rr < 2; ++rr) {
        int idx = tb * 2 + rr;
        int cout = idx >> 2, cs = idx & 3;
        *(uint4*)&Bh[cur][cout * 40 + (cs << 3)] = rg[rr];
        *(uint4*)&Bl[cur][cout * 40 + (cs << 3)] = rg[2 + rr];
      }
    }
  };

  issue_loads(0);
  for (int it = 0; it < NIT; ++it) {
    int cur = it & 1;
    write_lds(cur);                            // consumes rg (vmcnt waits auto)
    if (it + 1 < NIT) issue_loads(it + 1);     // in flight across the barrier
    asm volatile("s_waitcnt lgkmcnt(0)" ::: "memory");
    __builtin_amdgcn_s_barrier();
    __builtin_amdgcn_sched_barrier(0);
    short8 afh, afl, bfh[2], bfl[2];
    {
      int ra = ((wpx << 4) + cc) * 40 + (q << 3);
      afh = *(const short8*)&Ah[cur][ra];
      afl = *(const short8*)&Al[cur][ra];
    }
#pragma unroll
    for (int j = 0; j < 2; ++j) {
      int rb = ((wm << 5) + (j << 4) + cc) * 40 + (q << 3);
      bfh[j] = *(const short8*)&Bh[cur][rb];
      bfl[j] = *(const short8*)&Bl[cur][rb];
    }
#pragma unroll
    for (int j = 0; j < 2; ++j) {
      acc[j] = __builtin_amdgcn_mfma_f32_16x16x32_bf16(afh, bfl[j], acc[j], 0, 0, 0);
      acc[j] = __builtin_amdgcn_mfma_f32_16x16x32_bf16(afl, bfh[j], acc[j], 0, 0, 0);
      acc[j] = __builtin_amdgcn_mfma_f32_16x16x32_bf16(afh, bfh[j], acc[j], 0, 0, 0);
    }
  }
#pragma unroll
  for (int rgi = 0; rgi < 4; ++rgi) {
    int p = (ty << 6) + txb + (wpx << 4) + (q << 2) + rgi;
#pragma unroll
    for (int j = 0; j < 2; ++j) {
      int cout = (wm << 5) + (j << 4) + cc;
      float v = acc[j][rgi] + bias[cout];
      if (dorelu) v = fmaxf(v, 0.f);
      size_t oi = ((abase + p) << 6) + cout;
      if (res) v += res[oi];
      outp[oi] = v;
    }
  }
}

// ---------------- K8: out = dcf + xs*S
__global__ __launch_bounds__(256) void final_kernel(const float* __restrict__ dcf,
    const float* __restrict__ xs, const float* __restrict__ S, float* __restrict__ out)
{
  int tid = blockIdx.x * 256 + threadIdx.x;
  out[tid] = dcf[tid] + xs[tid] * S[tid >> 6];
}

extern "C" void kernel_launch(void* const* d_in, const int* in_sizes, int n_in,
                              void* d_out, int out_size, void* d_ws, size_t ws_size,
                              hipStream_t stream)
{
  (void)in_sizes; (void)n_in; (void)out_size; (void)ws_size;
  const float* c0     = (const float*)d_in[0];
  const float* f0     = (const float*)d_in[1];
  const float* c1     = (const float*)d_in[2];
  const float* head_w = (const float*)d_in[3];
  const float* head_b = (const float*)d_in[4];
  const float* rb_w1  = (const float*)d_in[5];
  const float* rb_b1  = (const float*)d_in[6];
  const float* rb_w2  = (const float*)d_in[7];
  const float* rb_b2  = (const float*)d_in[8];
  const float* tail_w = (const float*)d_in[9];
  const float* tail_b = (const float*)d_in[10];
  const float* sq_w   = (const float*)d_in[11];
  const float* sq_b   = (const float*)d_in[12];
  float* out = (float*)d_out;
  char* ws = (char*)d_ws;

  // ---- layout: 15,958,016 B total (unchanged) ----
  const size_t OFF_SS0  = 0;
  const size_t OFF_SS1  = 65536;
  const size_t OFF_INV0 = 131072;
  const size_t OFF_INV1 = 196608;
  const size_t OFF_S    = 262144;
  const size_t OFF_ARG  = 327680;
  const size_t OFF_PVAL = 393216;       // 512 KB
  const size_t OFF_PIDX = 917504;       // 512 KB
  const size_t OFF_WHH  = 1441792;      // head  hi 204800
  const size_t OFF_WHL  = 1646592;      // head  lo 204800
  const size_t OFF_W1H  = 1851392;      // rb1   hi 73728
  const size_t OFF_W1L  = 1925120;
  const size_t OFF_W2H  = 1998848;      // rb2   hi 73728
  const size_t OFF_W2L  = 2072576;
  const size_t OFF_WTH  = 2146304;      // tail  hi 204800
  const size_t OFF_WTL  = 2351104;
  const size_t OFF_WSH  = 2555904;      // sq    hi 409600
  const size_t OFF_WSL  = 2965504;
  const size_t OFF_P0H  = 3375104;
  const size_t OFF_P0L  = OFF_P0H + 2230272;   // 5,605,376
  const size_t OFF_P1H  = OFF_P0L + 2230272;   // 7,835,648
  const size_t OFF_P1L  = OFF_P1H + 2230272;   // 10,065,920 (end 12,296,192)
  const size_t OFF_SA   = 3375104;      // 4 MB: x1 -> T
  const size_t OFF_SB   = 7569408;      // 4 MB: hb -> dcf
  const size_t OFF_SC   = 11763712;     // 4 MB: xb -> xs

  float* ss0  = (float*)(ws + OFF_SS0);
  float* ss1  = (float*)(ws + OFF_SS1);
  float* inv0 = (float*)(ws + OFF_INV0);
  float* inv1 = (float*)(ws + OFF_INV1);
  float* Sbuf = (float*)(ws + OFF_S);
  int*   argb = (int*)(ws + OFF_ARG);
  float* pval = (float*)(ws + OFF_PVAL);
  int*   pidx = (int*)(ws + OFF_PIDX);
  u16* whh = (u16*)(ws + OFF_WHH); u16* whl = (u16*)(ws + OFF_WHL);
  u16* w1h = (u16*)(ws + OFF_W1H); u16* w1l = (u16*)(ws + OFF_W1L);
  u16* w2h = (u16*)(ws + OFF_W2H); u16* w2l = (u16*)(ws + OFF_W2L);
  u16* wth = (u16*)(ws + OFF_WTH); u16* wtl = (u16*)(ws + OFF_WTL);
  u16* wsh = (u16*)(ws + OFF_WSH); u16* wsl = (u16*)(ws + OFF_WSL);
  u16* p0h = (u16*)(ws + OFF_P0H); u16* p0l = (u16*)(ws + OFF_P0L);
  u16* p1h = (u16*)(ws + OFF_P1H); u16* p1l = (u16*)(ws + OFF_P1L);
  float* x1  = (float*)(ws + OFF_SA);
  float* Tb  = (float*)(ws + OFF_SA);
  float* hb  = (float*)(ws + OFF_SB);
  float* dcf = (float*)(ws + OFF_SB);
  float* xb  = (float*)(ws + OFF_SC);
  float* xsb = (float*)(ws + OFF_SC);

  dim3 b256(256);
  prep_ss<<<dim3(64), b256, 0, stream>>>(c0, c1, ss0, ss1);
  norm_kernel<<<dim3(64), b256, 0, stream>>>(ss0, ss1, inv0, inv1);
  split_pad_kernel<<<dim3(1089, BATCH), b256, 0, stream>>>(c0, c1, p0h, p0l, p1h, p1l);
  wprep<<<dim3(400), b256, 0, stream>>>(head_w, whh, whl, 64, 25, 102400);
  wprep<<<dim3(144), b256, 0, stream>>>(rb_w1 + 110592, w1h, w1l, 64, 9, 36864);
  wprep<<<dim3(144), b256, 0, stream>>>(rb_w2 + 110592, w2h, w2l, 64, 9, 36864);
  wprep<<<dim3(400), b256, 0, stream>>>(tail_w, wth, wtl, 64, 25, 102400);
  wprep<<<dim3(800), b256, 0, stream>>>(sq_w, wsh, wsl, 128, 25, 204800);

  corr_mfma<<<dim3(32, 8, BATCH), b256, 0, stream>>>(p0h, p0l, p1h, p1l, inv0, pval, pidx);
  reduce_kernel<<<dim3(64), b256, 0, stream>>>(pval, pidx, inv1, Sbuf, argb);

  // conv stack (only residual block 3 affects output); all NHWC.
  // Stream-ordered: these overwrite the padded-split region, which is dead now.
  dim3 cgrid(128, BATCH);
  conv_mfma<5, 2><<<cgrid, b256, 0, stream>>>(c0, c1, whh, whl, head_b, x1, nullptr, 0, 1);
  conv_mfma<3, 2><<<cgrid, b256, 0, stream>>>(x1, nullptr, w1h, w1l, rb_b1 + 192, hb, nullptr, 1, 0);
  conv_mfma<3, 2><<<cgrid, b256, 0, stream>>>(hb, nullptr, w2h, w2l, rb_b2 + 192, xb, x1, 0, 0);
  conv_mfma<5, 2><<<cgrid, b256, 0, stream>>>(xb, nullptr, wth, wtl, tail_b, dcf, x1, 0, 0);

  tgather_kernel<<<dim3(64, BATCH), b256, 0, stream>>>(f0, argb, Tb);   // x1 dead after conv4
  conv_mfma<5, 4><<<cgrid, b256, 0, stream>>>(dcf, Tb, wsh, wsl, sq_b, xsb, nullptr, 0, 0);

  final_kernel<<<dim3(4096), b256, 0, stream>>>(dcf, xsb, Sbuf, out);
}

// Round 4
// 514.433 us; speedup vs baseline: 1.2461x; 1.0290x over previous
//
#include <hip/hip_runtime.h>
#include <hip/hip_bf16.h>

// Texture_trans: patch-correlation texture transfer + residual conv stack.
// B=4, H=W=64, L=4096, C=64. ALL inputs/outputs fp32. Activations NHWC throughout.
// R16: (a) conv_mfma -> K=64 per iteration (full cin unit): 12 MFMA + 12 ds_read
// per barrier, NIT halved (25/9/50). LDS 55KB dbuf, stride 72 u16 (16B-aligned,
// conflict-floor). Same reg-staged single-barrier pipeline + verified fragments.
// (b) final_kernel fused into conv<5,4> epilogue (out = dcf + conv*S direct).
// (c) prep_ss fused into split_pad via 64-lane shfl reduce (lanes = channels).
// corr_mfma unchanged from R14/R15 (verified). Workspace: 15,958,016 B.

#define BATCH 4

typedef unsigned short u16;
typedef unsigned int   u32;
typedef __attribute__((ext_vector_type(8))) short short8;
typedef __attribute__((ext_vector_type(4))) float f32x4;

__device__ __forceinline__ void bsplit2(float a, float b, u32& ho, u32& lo) {
  __hip_bfloat16 ha = __float2bfloat16(a), hb = __float2bfloat16(b);
  float ra = a - __bfloat162float(ha), rb = b - __bfloat162float(hb);
  __hip_bfloat16 la = __float2bfloat16(ra), lb = __float2bfloat16(rb);
  ho = (u32)*(u16*)&ha | ((u32)*(u16*)&hb << 16);
  lo = (u32)*(u16*)&la | ((u32)*(u16*)&lb << 16);
}

__device__ __forceinline__ void gload_lds16(const void* g, void* l) {
  __builtin_amdgcn_global_load_lds((const __attribute__((address_space(1))) void*)g,
                                   (__attribute__((address_space(3))) void*)l, 16, 0, 0);
}

// ---------------- K2: 3x3 box-sum of sumsq -> 1/max(patch_norm, EPS)
__global__ __launch_bounds__(256) void norm_kernel(const float* __restrict__ ss0,
    const float* __restrict__ ss1, float* __restrict__ inv0, float* __restrict__ inv1)
{
  int tid = blockIdx.x * 256 + threadIdx.x;
  int b = tid >> 12, l = tid & 4095;
  int y = l >> 6, x = l & 63;
  int base = b << 12;
  float s0 = 0.f, s1 = 0.f;
  for (int dy = -1; dy <= 1; ++dy) {
    int yy = y + dy; if (yy < 0 || yy >= 64) continue;
    for (int dx = -1; dx <= 1; ++dx) {
      int xx = x + dx; if (xx < 0 || xx >= 64) continue;
      int ii = base + (yy << 6) + xx;
      s0 += ss0[ii]; s1 += ss1[ii];
    }
  }
  inv0[tid] = 1.f / fmaxf(sqrtf(s0), 1e-12f);
  inv1[tid] = 1.f / fmaxf(sqrtf(s1), 1e-12f);
}

// ---------------- K3: split fp32 -> bf16 hi + lo into ZERO-PADDED [B][66][66][64]
// + fused per-pixel channel sum-of-squares (lanes = channels, 64-lane shfl reduce).
__global__ __launch_bounds__(256) void split_pad_kernel(const float* __restrict__ c0,
    const float* __restrict__ c1, u16* __restrict__ p0h, u16* __restrict__ p0l,
    u16* __restrict__ p1h, u16* __restrict__ p1l,
    float* __restrict__ ss0, float* __restrict__ ss1)
{
  int b = blockIdx.y, t = threadIdx.x;
  int pix = blockIdx.x * 4 + (t >> 6);   // 0..4355 over 66x66
  int c = t & 63;
  int py = pix / 66, px = pix - py * 66;
  size_t d = ((size_t)b * 4356 + pix) * 64 + c;
  bool interior = (py >= 1 && py <= 64 && px >= 1 && px <= 64);
  float v0 = 0.f, v1 = 0.f;
  if (interior) {
    size_t s = (((size_t)b << 12) + ((py - 1) << 6) + (px - 1)) * 64 + c;
    v0 = c0[s]; v1 = c1[s];
  }
  __hip_bfloat16 h = __float2bfloat16(v0);
  float r = v0 - __bfloat162float(h);
  __hip_bfloat16 lo = __float2bfloat16(r);
  p0h[d] = *(u16*)&h; p0l[d] = *(u16*)&lo;
  h = __float2bfloat16(v1);
  r = v1 - __bfloat162float(h);
  lo = __float2bfloat16(r);
  p1h[d] = *(u16*)&h; p1l[d] = *(u16*)&lo;
  // fused sum-of-squares (wave = one pixel's 64 channels)
  float s0 = v0 * v0, s1 = v1 * v1;
#pragma unroll
  for (int off = 32; off; off >>= 1) {
    s0 += __shfl_xor(s0, off);
    s1 += __shfl_xor(s1, off);
  }
  if (c == 0 && interior) {
    int sstid = (b << 12) + ((py - 1) << 6) + (px - 1);
    ss0[sstid] = s0;
    ss1[sstid] = s1;
  }
}

// ---------------- K3b: weight transpose+split OIHW fp32 -> [tap][cout][cin] bf16 hi/lo
__global__ __launch_bounds__(256) void wprep(const float* __restrict__ src,
    u16* __restrict__ wh, u16* __restrict__ wl, int Cin, int KK, int n)
{
  int i = blockIdx.x * 256 + threadIdx.x;
  if (i >= n) return;
  int per = Cin * KK;
  int cout = i / per;
  int rem = i - cout * per;
  int cin = rem / KK;
  int tap = rem - cin * KK;
  float x = src[i];
  __hip_bfloat16 h = __float2bfloat16(x);
  float r = x - __bfloat162float(h);
  __hip_bfloat16 lo = __float2bfloat16(r);
  int d = (tap * 64 + cout) * Cin + cin;
  wh[d] = *(u16*)&h;
  wl[d] = *(u16*)&lo;
}

// ---------------- K4: MFMA corr. Double-buffered DMA pipeline (unchanged R14/R15).
__global__ __launch_bounds__(256) void corr_mfma(const u16* __restrict__ p0h,
    const u16* __restrict__ p0l, const u16* __restrict__ p1h, const u16* __restrict__ p1l,
    const float* __restrict__ inv0, float* __restrict__ pval, int* __restrict__ pidx)
{
  __shared__ __align__(16) u16 smem[32768];   // 64 KB: 2 x (4 matrices x 4096)
  int mt = blockIdx.x, lt = blockIdx.y, b = blockIdx.z;
  int t = threadIdx.x;
  int lane = t & 63, w = t >> 6;
  int wl = w >> 1, wm = w & 1;
  int cc = lane & 15, q = lane >> 4;
  const size_t boff = (size_t)b * 278784;     // 66*66*64
  const u16* msrc = (w == 0) ? p0h : (w == 1) ? p0l : (w == 2) ? p1h : p1l;
  msrc += boff;
  const float* inv0b = inv0 + (b << 12);
  int isB = w >> 1;

  int srow0 = lane >> 2;                      // row within 16-row chunk
  int cs_g  = (lane & 3) ^ ((lane >> 3) & 3); // source chunk for this lane's slot
  int sw    = (cc >> 1) & 3;                  // read-side swizzle key

  auto stage = [&](int ssub, int sph, u16* dst) {
    int r = sph >> 1, hh = sph & 1;
    int ki = r / 3, kj = r - ki * 3;
    int pb = isB ? (mt << 7) : ((lt << 9) + (ssub << 7));
#pragma unroll
    for (int it = 0; it < 8; ++it) {
      int p = pb + (it << 4) + srow0;
      int ypad = (p >> 6) + ki, xpad = (p & 63) + kj;
      const u16* g = msrc + (((size_t)(ypad * 66 + xpad)) << 6) + (hh << 5) + (cs_g << 3);
      gload_lds16(g, dst + (it << 9));
    }
  };

  float bval[4] = {-1e30f, -1e30f, -1e30f, -1e30f};
  int   bidx[4] = {0, 0, 0, 0};

  stage(0, 0, smem + (w << 12));

  for (int sub = 0; sub < 4; ++sub) {
    int row0 = (lt << 9) + (sub << 7);
    f32x4 acc[4][4];
#pragma unroll
    for (int i = 0; i < 4; ++i)
#pragma unroll
      for (int j = 0; j < 4; ++j) acc[i][j] = (f32x4){0.f, 0.f, 0.f, 0.f};

    for (int ph = 0; ph < 18; ++ph) {
      int g = sub * 18 + ph;
      int nxt = g + 1;
      if (nxt < 72) {
        int np = ph + 1, ns = sub;
        if (np == 18) { np = 0; ++ns; }
        stage(ns, np, smem + ((nxt & 1) << 14) + (w << 12));
        asm volatile("s_waitcnt vmcnt(8)" ::: "memory");   // phase g landed; g+1 in flight
      } else {
        asm volatile("s_waitcnt vmcnt(0)" ::: "memory");
      }
      __builtin_amdgcn_s_barrier();
      __builtin_amdgcn_sched_barrier(0);
      const u16* bb = smem + ((g & 1) << 14);
      short8 afh[4], afl[4], bfh[4], bfl[4];
#pragma unroll
      for (int i = 0; i < 4; ++i) {
        int ra = (((wl << 6) + (i << 4) + cc) << 5) + ((q ^ sw) << 3);
        afh[i] = *(const short8*)(&bb[ra]);
        afl[i] = *(const short8*)(&bb[4096 + ra]);
      }
#pragma unroll
      for (int j = 0; j < 4; ++j) {
        int rb = (((wm << 6) + (j << 4) + cc) << 5) + ((q ^ sw) << 3);
        bfh[j] = *(const short8*)(&bb[8192 + rb]);
        bfl[j] = *(const short8*)(&bb[12288 + rb]);
      }
#pragma unroll
      for (int i = 0; i < 4; ++i)
#pragma unroll
        for (int j = 0; j < 4; ++j) {
          acc[i][j] = __builtin_amdgcn_mfma_f32_16x16x32_bf16(afh[i], bfl[j], acc[i][j], 0, 0, 0);
          acc[i][j] = __builtin_amdgcn_mfma_f32_16x16x32_bf16(afl[i], bfh[j], acc[i][j], 0, 0, 0);
          acc[i][j] = __builtin_amdgcn_mfma_f32_16x16x32_bf16(afh[i], bfh[j], acc[i][j], 0, 0, 0);
        }
      __builtin_amdgcn_sched_barrier(0);
      __builtin_amdgcn_s_barrier();          // readers done before buf re-staged
    }
#pragma unroll
    for (int i = 0; i < 4; ++i) {
#pragma unroll
      for (int rg = 0; rg < 4; ++rg) {
        int l = row0 + (wl << 6) + (i << 4) + (q << 2) + rg;
        float sc = inv0b[l];
#pragma unroll
        for (int j = 0; j < 4; ++j) {
          float v = acc[i][j][rg] * sc;
          if (v > bval[j]) { bval[j] = v; bidx[j] = l; }
        }
      }
    }
  }

  __syncthreads();                            // tiles dead; alias reduce buffers
  float* lval = (float*)smem;                 // 4096 B
  int*   lidx = (int*)((char*)smem + 4096);   // 4096 B
  int slot = (wl << 2) + q;
#pragma unroll
  for (int j = 0; j < 4; ++j) {
    int col = (wm << 6) + (j << 4) + cc;
    lval[col * 8 + slot] = bval[j];
    lidx[col * 8 + slot] = bidx[j];
  }
  __syncthreads();
  if (t < 128) {
    float bv = -1e30f; int bi = 0x7FFFFFFF;
    for (int s = 0; s < 8; ++s) {
      float v = lval[t * 8 + s]; int id = lidx[t * 8 + s];
      if (v > bv || (v == bv && id < bi)) { bv = v; bi = id; }
    }
    size_t o = (size_t)(((b << 3) + lt) << 12) + (mt << 7) + t;
    pval[o] = bv; pidx[o] = bi;
  }
}

// ---------------- K5: reduce partials -> S, argmax
__global__ __launch_bounds__(256) void reduce_kernel(const float* __restrict__ pval,
    const int* __restrict__ pidx, const float* __restrict__ inv1,
    float* __restrict__ S, int* __restrict__ arg)
{
  int tid = blockIdx.x * 256 + threadIdx.x;
  int b = tid >> 12, m = tid & 4095;
  float bv = -1e30f; int bi = 0x7FFFFFFF;
  for (int lt = 0; lt < 8; ++lt) {
    size_t o = (size_t)(((b << 3) + lt) << 12) + m;
    float v = pval[o]; int id = pidx[o];
    if (v > bv || (v == bv && id < bi)) { bv = v; bi = id; }
  }
  S[tid] = bv * inv1[tid];
  arg[tid] = ((unsigned)bi < 4096u) ? bi : 0;
}

// ---------------- K6: T = fold3(gather(f0_unfold, arg))/9 -> NHWC fp32
__global__ __launch_bounds__(256) void tgather_kernel(const float* __restrict__ f0,
    const int* __restrict__ arg, float* __restrict__ T)
{
  __shared__ int a3[192];
  int y = blockIdx.x, b = blockIdx.y, t = threadIdx.x;
  if (t < 192) {
    int r = t >> 6, xx = t & 63;
    int yy = y + r - 1;
    a3[t] = (yy >= 0 && yy < 64) ? arg[(b << 12) + (yy << 6) + xx] : 0;
  }
  __syncthreads();
  int c = t & 63, pg = t >> 6;
  for (int it = 0; it < 16; ++it) {
    int px = pg + (it << 2);
    float sum = 0.f;
#pragma unroll
    for (int ki = 0; ki < 3; ++ki) {
      int yn = y + 1 - ki;
      if (yn < 0 || yn >= 64) continue;
#pragma unroll
      for (int kj = 0; kj < 3; ++kj) {
        int xn = px + 1 - kj;
        if (xn < 0 || xn >= 64) continue;
        int p = a3[((2 - ki) << 6) + xn];
        int sy = (p >> 6) + ki - 1, sx = (p & 63) + kj - 1;
        if (sy >= 0 && sy < 64 && sx >= 0 && sx < 64)
          sum += f0[((((size_t)b << 12) + (sy << 6) + sx) << 6) + c];
      }
    }
    T[((((size_t)b << 12) + (y << 6) + px)) * 64 + c] = sum * (1.f / 9.f);
  }
}

// ---------------- K7: implicit-GEMM MFMA conv, NHWC fp32 act, pre-split bf16 weights.
// R16: K=64 per iteration. Tile = 32 px x 64 cout; grid (128, B), 2 blocks/CU.
// Per iteration (tap, kh): write LDS[cur] (A: 32px x 64cin, B: 64cout x 64cin, hi/lo)
// -> issue next iter's global loads to regs -> lgkmcnt(0) + s_barrier (vmcnt NOT
// drained) -> 12 ds_read + 12 MFMA (2 k-steps). Stride 72 u16 (144B, 16B-aligned).
// smul: fused final (out = res + conv*smul). Fragment math per verified pattern.
template<int KS, int CINCH>
__global__ __launch_bounds__(256) void conv_mfma(const float* __restrict__ in0,
    const float* __restrict__ in1, const u16* __restrict__ whp, const u16* __restrict__ wlp,
    const float* __restrict__ bias, float* __restrict__ outp,
    const float* __restrict__ res, const float* __restrict__ smul, int dorelu, int dm)
{
  constexpr int P = KS / 2;
  constexpr int CIN = CINCH * 32;
  constexpr int NKH = CINCH / 2;              // # of 64-cin units
  constexpr int NIT = KS * KS * NKH;
  constexpr int AST = 72;                     // row stride in u16 (144 B, 16B-aligned)
  __shared__ __align__(16) u16 Ah[2][32 * AST], Al[2][32 * AST];
  __shared__ __align__(16) u16 Bh[2][64 * AST], Bl[2][64 * AST];
  int tile = blockIdx.x, b = blockIdx.y;      // y = tile>>1, px half = tile&1
  int t = threadIdx.x;
  int lane = t & 63, w = t >> 6;
  int wpx = w >> 1, wm = w & 1;
  int cc = lane & 15, q = lane >> 4;
  int ty = tile >> 1, txb = (tile & 1) << 5;
  const size_t abase = (size_t)b << 12;
  f32x4 acc[2];
  acc[0] = (f32x4){0.f, 0.f, 0.f, 0.f};
  acc[1] = (f32x4){0.f, 0.f, 0.f, 0.f};

  uint4 rg[8];                                // staging regs
  int arow = t >> 2, acs = t & 3;             // A mapping (t<128): 16-ch quarter
  int tb = t - 128;                           // B mapping (t>=128)
  int brow = tb >> 1, bhalf = tb & 1;         // 64 rows x 2 halves of 32 ch

  auto issue_loads = [&](int itn) {
    int tapn = (NKH == 1) ? itn : (itn >> 1);
    int kh   = (NKH == 1) ? 0 : (itn & 1);
    int ki = tapn / KS, kj = tapn - ki * KS;
    if (t < 128) {
#pragma unroll
      for (int k = 0; k < 8; ++k) rg[k] = make_uint4(0u, 0u, 0u, 0u);
      int iy = ty + ki - P;
      int ix = txb + arow + kj - P;
      if ((unsigned)iy < 64u && (unsigned)ix < 64u) {
        size_t base = (abase + (iy << 6) + ix) << 6;
        int cg = kh * 64 + acs * 16;
        if (dm) {
#pragma unroll
          for (int k = 0; k < 4; ++k) {
            rg[k]     = *(const uint4*)(in0 + base + cg + 4 * k);
            rg[4 + k] = *(const uint4*)(in1 + base + cg + 4 * k);
          }
        } else {
          const float* sp = (CINCH == 4 && kh == 1) ? (in1 + base + (cg - 64))
                                                    : (in0 + base + cg);
#pragma unroll
          for (int k = 0; k < 4; ++k) rg[k] = *(const uint4*)(sp + 4 * k);
        }
      }
    } else {
      size_t so = (size_t)(tapn * 64 + brow) * CIN + kh * 64 + bhalf * 32;
#pragma unroll
      for (int k = 0; k < 4; ++k) {
        rg[k]     = *(const uint4*)&whp[so + 8 * k];
        rg[4 + k] = *(const uint4*)&wlp[so + 8 * k];
      }
    }
  };

  auto write_lds = [&](int cur) {
    if (t < 128) {
      float v[16];
      if (dm) {
#pragma unroll
        for (int k = 0; k < 4; ++k)
#pragma unroll
          for (int e = 0; e < 4; ++e)
            v[k * 4 + e] = __uint_as_float((&rg[4 + k].x)[e]) - __uint_as_float((&rg[k].x)[e]);
      } else {
#pragma unroll
        for (int k = 0; k < 4; ++k)
#pragma unroll
          for (int e = 0; e < 4; ++e)
            v[k * 4 + e] = __uint_as_float((&rg[k].x)[e]);
      }
      uint4 uh0, ul0, uh1, ul1;
      bsplit2(v[0], v[1], uh0.x, ul0.x);
      bsplit2(v[2], v[3], uh0.y, ul0.y);
      bsplit2(v[4], v[5], uh0.z, ul0.z);
      bsplit2(v[6], v[7], uh0.w, ul0.w);
      bsplit2(v[8], v[9], uh1.x, ul1.x);
      bsplit2(v[10], v[11], uh1.y, ul1.y);
      bsplit2(v[12], v[13], uh1.z, ul1.z);
      bsplit2(v[14], v[15], uh1.w, ul1.w);
      int o = arow * AST + acs * 16;
      *(uint4*)&Ah[cur][o]     = uh0;
      *(uint4*)&Ah[cur][o + 8] = uh1;
      *(uint4*)&Al[cur][o]     = ul0;
      *(uint4*)&Al[cur][o + 8] = ul1;
    } else {
      int o = brow * AST + bhalf * 32;
#pragma unroll
      for (int k = 0; k < 4; ++k) {
        *(uint4*)&Bh[cur][o + 8 * k] = rg[k];
        *(uint4*)&Bl[cur][o + 8 * k] = rg[4 + k];
      }
    }
  };

  issue_loads(0);
  for (int it = 0; it < NIT; ++it) {
    int cur = it & 1;
    write_lds(cur);                            // consumes rg (vmcnt waits auto)
    if (it + 1 < NIT) issue_loads(it + 1);     // in flight across the barrier
    asm volatile("s_waitcnt lgkmcnt(0)" ::: "memory");
    __builtin_amdgcn_s_barrier();
    __builtin_amdgcn_sched_barrier(0);
    short8 afh[2], afl[2], bfh[2][2], bfl[2][2];
#pragma unroll
    for (int ks = 0; ks < 2; ++ks) {
      int ra = ((wpx << 4) + cc) * AST + ks * 32 + (q << 3);
      afh[ks] = *(const short8*)&Ah[cur][ra];
      afl[ks] = *(const short8*)&Al[cur][ra];
#pragma unroll
      for (int j = 0; j < 2; ++j) {
        int rb = ((wm << 5) + (j << 4) + cc) * AST + ks * 32 + (q << 3);
        bfh[j][ks] = *(const short8*)&Bh[cur][rb];
        bfl[j][ks] = *(const short8*)&Bl[cur][rb];
      }
    }
#pragma unroll
    for (int ks = 0; ks < 2; ++ks) {
      acc[0] = __builtin_amdgcn_mfma_f32_16x16x32_bf16(afh[ks], bfl[0][ks], acc[0], 0, 0, 0);
      acc[1] = __builtin_amdgcn_mfma_f32_16x16x32_bf16(afh[ks], bfl[1][ks], acc[1], 0, 0, 0);
      acc[0] = __builtin_amdgcn_mfma_f32_16x16x32_bf16(afl[ks], bfh[0][ks], acc[0], 0, 0, 0);
      acc[1] = __builtin_amdgcn_mfma_f32_16x16x32_bf16(afl[ks], bfh[1][ks], acc[1], 0, 0, 0);
      acc[0] = __builtin_amdgcn_mfma_f32_16x16x32_bf16(afh[ks], bfh[0][ks], acc[0], 0, 0, 0);
      acc[1] = __builtin_amdgcn_mfma_f32_16x16x32_bf16(afh[ks], bfh[1][ks], acc[1], 0, 0, 0);
    }
  }
#pragma unroll
  for (int rgi = 0; rgi < 4; ++rgi) {
    int p = (ty << 6) + txb + (wpx << 4) + (q << 2) + rgi;
#pragma unroll
    for (int j = 0; j < 2; ++j) {
      int cout = (wm << 5) + (j << 4) + cc;
      float v = acc[j][rgi] + bias[cout];
      if (dorelu) v = fmaxf(v, 0.f);
      size_t oi = ((abase + p) << 6) + cout;
      if (smul) v = res[oi] + v * smul[abase + p];
      else if (res) v += res[oi];
      outp[oi] = v;
    }
  }
}

extern "C" void kernel_launch(void* const* d_in, const int* in_sizes, int n_in,
                              void* d_out, int out_size, void* d_ws, size_t ws_size,
                              hipStream_t stream)
{
  (void)in_sizes; (void)n_in; (void)out_size; (void)ws_size;
  const float* c0     = (const float*)d_in[0];
  const float* f0     = (const float*)d_in[1];
  const float* c1     = (const float*)d_in[2];
  const float* head_w = (const float*)d_in[3];
  const float* head_b = (const float*)d_in[4];
  const float* rb_w1  = (const float*)d_in[5];
  const float* rb_b1  = (const float*)d_in[6];
  const float* rb_w2  = (const float*)d_in[7];
  const float* rb_b2  = (const float*)d_in[8];
  const float* tail_w = (const float*)d_in[9];
  const float* tail_b = (const float*)d_in[10];
  const float* sq_w   = (const float*)d_in[11];
  const float* sq_b   = (const float*)d_in[12];
  float* out = (float*)d_out;
  char* ws = (char*)d_ws;

  // ---- layout: 15,958,016 B total (unchanged) ----
  const size_t OFF_SS0  = 0;
  const size_t OFF_SS1  = 65536;
  const size_t OFF_INV0 = 131072;
  const size_t OFF_INV1 = 196608;
  const size_t OFF_S    = 262144;
  const size_t OFF_ARG  = 327680;
  const size_t OFF_PVAL = 393216;       // 512 KB
  const size_t OFF_PIDX = 917504;       // 512 KB
  const size_t OFF_WHH  = 1441792;      // head  hi 204800
  const size_t OFF_WHL  = 1646592;      // head  lo 204800
  const size_t OFF_W1H  = 1851392;      // rb1   hi 73728
  const size_t OFF_W1L  = 1925120;
  const size_t OFF_W2H  = 1998848;      // rb2   hi 73728
  const size_t OFF_W2L  = 2072576;
  const size_t OFF_WTH  = 2146304;      // tail  hi 204800
  const size_t OFF_WTL  = 2351104;
  const size_t OFF_WSH  = 2555904;      // sq    hi 409600
  const size_t OFF_WSL  = 2965504;
  const size_t OFF_P0H  = 3375104;
  const size_t OFF_P0L  = OFF_P0H + 2230272;   // 5,605,376
  const size_t OFF_P1H  = OFF_P0L + 2230272;   // 7,835,648
  const size_t OFF_P1L  = OFF_P1H + 2230272;   // 10,065,920 (end 12,296,192)
  const size_t OFF_SA   = 3375104;      // 4 MB: x1 -> T
  const size_t OFF_SB   = 7569408;      // 4 MB: hb -> dcf
  const size_t OFF_SC   = 11763712;     // 4 MB: xb

  float* ss0  = (float*)(ws + OFF_SS0);
  float* ss1  = (float*)(ws + OFF_SS1);
  float* inv0 = (float*)(ws + OFF_INV0);
  float* inv1 = (float*)(ws + OFF_INV1);
  float* Sbuf = (float*)(ws + OFF_S);
  int*   argb = (int*)(ws + OFF_ARG);
  float* pval = (float*)(ws + OFF_PVAL);
  int*   pidx = (int*)(ws + OFF_PIDX);
  u16* whh = (u16*)(ws + OFF_WHH); u16* whl = (u16*)(ws + OFF_WHL);
  u16* w1h = (u16*)(ws + OFF_W1H); u16* w1l = (u16*)(ws + OFF_W1L);
  u16* w2h = (u16*)(ws + OFF_W2H); u16* w2l = (u16*)(ws + OFF_W2L);
  u16* wth = (u16*)(ws + OFF_WTH); u16* wtl = (u16*)(ws + OFF_WTL);
  u16* wsh = (u16*)(ws + OFF_WSH); u16* wsl = (u16*)(ws + OFF_WSL);
  u16* p0h = (u16*)(ws + OFF_P0H); u16* p0l = (u16*)(ws + OFF_P0L);
  u16* p1h = (u16*)(ws + OFF_P1H); u16* p1l = (u16*)(ws + OFF_P1L);
  float* x1  = (float*)(ws + OFF_SA);
  float* Tb  = (float*)(ws + OFF_SA);
  float* hb  = (float*)(ws + OFF_SB);
  float* dcf = (float*)(ws + OFF_SB);
  float* xb  = (float*)(ws + OFF_SC);

  dim3 b256(256);
  split_pad_kernel<<<dim3(1089, BATCH), b256, 0, stream>>>(c0, c1, p0h, p0l, p1h, p1l, ss0, ss1);
  norm_kernel<<<dim3(64), b256, 0, stream>>>(ss0, ss1, inv0, inv1);
  wprep<<<dim3(400), b256, 0, stream>>>(head_w, whh, whl, 64, 25, 102400);
  wprep<<<dim3(144), b256, 0, stream>>>(rb_w1 + 110592, w1h, w1l, 64, 9, 36864);
  wprep<<<dim3(144), b256, 0, stream>>>(rb_w2 + 110592, w2h, w2l, 64, 9, 36864);
  wprep<<<dim3(400), b256, 0, stream>>>(tail_w, wth, wtl, 64, 25, 102400);
  wprep<<<dim3(800), b256, 0, stream>>>(sq_w, wsh, wsl, 128, 25, 204800);

  corr_mfma<<<dim3(32, 8, BATCH), b256, 0, stream>>>(p0h, p0l, p1h, p1l, inv0, pval, pidx);
  reduce_kernel<<<dim3(64), b256, 0, stream>>>(pval, pidx, inv1, Sbuf, argb);

  // conv stack (only residual block 3 affects output); all NHWC.
  // Stream-ordered: these overwrite the padded-split region, which is dead now.
  dim3 cgrid(128, BATCH);
  conv_mfma<5, 2><<<cgrid, b256, 0, stream>>>(c0, c1, whh, whl, head_b, x1, nullptr, nullptr, 0, 1);
  conv_mfma<3, 2><<<cgrid, b256, 0, stream>>>(x1, nullptr, w1h, w1l, rb_b1 + 192, hb, nullptr, nullptr, 1, 0);
  conv_mfma<3, 2><<<cgrid, b256, 0, stream>>>(hb, nullptr, w2h, w2l, rb_b2 + 192, xb, x1, nullptr, 0, 0);
  conv_mfma<5, 2><<<cgrid, b256, 0, stream>>>(xb, nullptr, wth, wtl, tail_b, dcf, x1, nullptr, 0, 0);

  tgather_kernel<<<dim3(64, BATCH), b256, 0, stream>>>(f0, argb, Tb);   // x1 dead after conv4
  // conv5 with fused final: out = dcf + conv*S, written directly to output (NLC==NHWC)
  conv_mfma<5, 4><<<cgrid, b256, 0, stream>>>(dcf, Tb, wsh, wsl, sq_b, out, dcf, Sbuf, 0, 0);
}

// Round 5
// 506.595 us; speedup vs baseline: 1.2654x; 1.0155x over previous
//
#include <hip/hip_runtime.h>
#include <hip/hip_bf16.h>

// Texture_trans: patch-correlation texture transfer + residual conv stack.
// B=4, H=W=64, L=4096, C=64. ALL inputs/outputs fp32. Activations NHWC throughout.
// R17: corr_mfma -> 8 waves/block (512 thr): per-wave acc 2x4 frags (A-quarter x
// B-half), 16 waves/CU (~42% occ) to hide ds_read latency + barrier sync. Staging
// split 4 gloads/wave (vmcnt(4)); per-lane base pointers precomputed, per-phase
// address = base + uniform scalar offset (kills ~70 VALU/phase). setprio(1)
// around MFMA cluster. Tile/swizzle/barrier structure identical to verified R14.
// Convs/others unchanged from R16 (passed). Workspace: 15,958,016 B.

#define BATCH 4

typedef unsigned short u16;
typedef unsigned int   u32;
typedef __attribute__((ext_vector_type(8))) short short8;
typedef __attribute__((ext_vector_type(4))) float f32x4;

__device__ __forceinline__ void bsplit2(float a, float b, u32& ho, u32& lo) {
  __hip_bfloat16 ha = __float2bfloat16(a), hb = __float2bfloat16(b);
  float ra = a - __bfloat162float(ha), rb = b - __bfloat162float(hb);
  __hip_bfloat16 la = __float2bfloat16(ra), lb = __float2bfloat16(rb);
  ho = (u32)*(u16*)&ha | ((u32)*(u16*)&hb << 16);
  lo = (u32)*(u16*)&la | ((u32)*(u16*)&lb << 16);
}

__device__ __forceinline__ void gload_lds16(const void* g, void* l) {
  __builtin_amdgcn_global_load_lds((const __attribute__((address_space(1))) void*)g,
                                   (__attribute__((address_space(3))) void*)l, 16, 0, 0);
}

// ---------------- K2: 3x3 box-sum of sumsq -> 1/max(patch_norm, EPS)
__global__ __launch_bounds__(256) void norm_kernel(const float* __restrict__ ss0,
    const float* __restrict__ ss1, float* __restrict__ inv0, float* __restrict__ inv1)
{
  int tid = blockIdx.x * 256 + threadIdx.x;
  int b = tid >> 12, l = tid & 4095;
  int y = l >> 6, x = l & 63;
  int base = b << 12;
  float s0 = 0.f, s1 = 0.f;
  for (int dy = -1; dy <= 1; ++dy) {
    int yy = y + dy; if (yy < 0 || yy >= 64) continue;
    for (int dx = -1; dx <= 1; ++dx) {
      int xx = x + dx; if (xx < 0 || xx >= 64) continue;
      int ii = base + (yy << 6) + xx;
      s0 += ss0[ii]; s1 += ss1[ii];
    }
  }
  inv0[tid] = 1.f / fmaxf(sqrtf(s0), 1e-12f);
  inv1[tid] = 1.f / fmaxf(sqrtf(s1), 1e-12f);
}

// ---------------- K3: split fp32 -> bf16 hi + lo into ZERO-PADDED [B][66][66][64]
// + fused per-pixel channel sum-of-squares (lanes = channels, 64-lane shfl reduce).
__global__ __launch_bounds__(256) void split_pad_kernel(const float* __restrict__ c0,
    const float* __restrict__ c1, u16* __restrict__ p0h, u16* __restrict__ p0l,
    u16* __restrict__ p1h, u16* __restrict__ p1l,
    float* __restrict__ ss0, float* __restrict__ ss1)
{
  int b = blockIdx.y, t = threadIdx.x;
  int pix = blockIdx.x * 4 + (t >> 6);   // 0..4355 over 66x66
  int c = t & 63;
  int py = pix / 66, px = pix - py * 66;
  size_t d = ((size_t)b * 4356 + pix) * 64 + c;
  bool interior = (py >= 1 && py <= 64 && px >= 1 && px <= 64);
  float v0 = 0.f, v1 = 0.f;
  if (interior) {
    size_t s = (((size_t)b << 12) + ((py - 1) << 6) + (px - 1)) * 64 + c;
    v0 = c0[s]; v1 = c1[s];
  }
  __hip_bfloat16 h = __float2bfloat16(v0);
  float r = v0 - __bfloat162float(h);
  __hip_bfloat16 lo = __float2bfloat16(r);
  p0h[d] = *(u16*)&h; p0l[d] = *(u16*)&lo;
  h = __float2bfloat16(v1);
  r = v1 - __bfloat162float(h);
  lo = __float2bfloat16(r);
  p1h[d] = *(u16*)&h; p1l[d] = *(u16*)&lo;
  float s0 = v0 * v0, s1 = v1 * v1;
#pragma unroll
  for (int off = 32; off; off >>= 1) {
    s0 += __shfl_xor(s0, off);
    s1 += __shfl_xor(s1, off);
  }
  if (c == 0 && interior) {
    int sstid = (b << 12) + ((py - 1) << 6) + (px - 1);
    ss0[sstid] = s0;
    ss1[sstid] = s1;
  }
}

// ---------------- K3b: weight transpose+split OIHW fp32 -> [tap][cout][cin] bf16 hi/lo
__global__ __launch_bounds__(256) void wprep(const float* __restrict__ src,
    u16* __restrict__ wh, u16* __restrict__ wl, int Cin, int KK, int n)
{
  int i = blockIdx.x * 256 + threadIdx.x;
  if (i >= n) return;
  int per = Cin * KK;
  int cout = i / per;
  int rem = i - cout * per;
  int cin = rem / KK;
  int tap = rem - cin * KK;
  float x = src[i];
  __hip_bfloat16 h = __float2bfloat16(x);
  float r = x - __bfloat162float(h);
  __hip_bfloat16 lo = __float2bfloat16(r);
  int d = (tap * 64 + cout) * Cin + cin;
  wh[d] = *(u16*)&h;
  wl[d] = *(u16*)&lo;
}

// ---------------- K4: MFMA corr. 8 waves, double-buffered DMA pipeline.
// Wave w: staging matrix = w>>1 (0:A_hi 1:A_lo 2:B_hi 3:B_lo), half = w&1
// (4 gload_lds/phase). Compute: A-quarter wa = w>>1 (32 rows, 2 frags),
// B-half wm = w&1 (64 cols, 4 frags). Swizzled chunk layout as R13 (verified).
__global__ __launch_bounds__(512) void corr_mfma(const u16* __restrict__ p0h,
    const u16* __restrict__ p0l, const u16* __restrict__ p1h, const u16* __restrict__ p1l,
    const float* __restrict__ inv0, float* __restrict__ pval, int* __restrict__ pidx)
{
  __shared__ __align__(16) u16 smem[32768];   // 64 KB: 2 buf x (4 matrices x 4096)
  int mt = blockIdx.x, lt = blockIdx.y, b = blockIdx.z;
  int t = threadIdx.x;
  int lane = t & 63, w = t >> 6;              // w in 0..7
  int wa = w >> 1, wm = w & 1;                // A-quarter / B-half (compute)
  int mat = w >> 1, half = w & 1;             // staging matrix / half
  int cc = lane & 15, q = lane >> 4;
  const size_t boff = (size_t)b * 278784;     // 66*66*64
  const u16* msrc = (mat == 0) ? p0h : (mat == 1) ? p0l : (mat == 2) ? p1h : p1l;
  msrc += boff;
  const float* inv0b = inv0 + (b << 12);
  int isB = mat >> 1;

  int srow0 = lane >> 2;                      // row within 16-row chunk
  int cs_g  = (lane & 3) ^ ((lane >> 3) & 3); // source chunk for this lane's slot
  int sw    = (cc >> 1) & 3;                  // read-side swizzle key

  // per-lane base pointers for this wave's 4 staged chunks (sub/phase-independent)
  const u16* gb[4];
#pragma unroll
  for (int ii = 0; ii < 4; ++ii) {
    int k = ((half * 4 + ii) << 4) + srow0;   // pixel offset within 128-row tile
    gb[ii] = msrc + ((((k >> 6) * 66) + (k & 63)) << 6) + (cs_g << 3);
  }

  // stage: 4 DMA loads; address = gb[ii] + uniform scalar offset
  auto stage = [&](int ssub, int sph, u16* dstbase) {
    int r = sph >> 1, hh = sph & 1;
    int ki = r / 3, kj = r - ki * 3;
    int pbr = isB ? (mt << 1) : ((lt << 3) + (ssub << 1));   // pb>>6 (rows)
    int uoff = (((pbr + ki) * 66 + kj) << 6) + (hh << 5);    // wave-uniform
#pragma unroll
    for (int ii = 0; ii < 4; ++ii)
      gload_lds16(gb[ii] + uoff, dstbase + ((half * 4 + ii) << 9));
  };

  float bval[4] = {-1e30f, -1e30f, -1e30f, -1e30f};
  int   bidx[4] = {0, 0, 0, 0};

  stage(0, 0, smem + (mat << 12));            // prologue into buffer 0

  for (int sub = 0; sub < 4; ++sub) {
    int row0 = (lt << 9) + (sub << 7);
    f32x4 acc[2][4];
#pragma unroll
    for (int i = 0; i < 2; ++i)
#pragma unroll
      for (int j = 0; j < 4; ++j) acc[i][j] = (f32x4){0.f, 0.f, 0.f, 0.f};

    for (int ph = 0; ph < 18; ++ph) {
      int g = sub * 18 + ph;
      int nxt = g + 1;
      if (nxt < 72) {
        int np = ph + 1, ns = sub;
        if (np == 18) { np = 0; ++ns; }
        stage(ns, np, smem + ((nxt & 1) << 14) + (mat << 12));
        asm volatile("s_waitcnt vmcnt(4)" ::: "memory");   // phase g landed; g+1 in flight
      } else {
        asm volatile("s_waitcnt vmcnt(0)" ::: "memory");
      }
      __builtin_amdgcn_s_barrier();
      __builtin_amdgcn_sched_barrier(0);
      const u16* bb = smem + ((g & 1) << 14);
      short8 afh[2], afl[2], bfh[4], bfl[4];
#pragma unroll
      for (int i = 0; i < 2; ++i) {
        int ra = (((wa << 5) + (i << 4) + cc) << 5) + ((q ^ sw) << 3);
        afh[i] = *(const short8*)(&bb[ra]);
        afl[i] = *(const short8*)(&bb[4096 + ra]);
      }
#pragma unroll
      for (int j = 0; j < 4; ++j) {
        int rb = (((wm << 6) + (j << 4) + cc) << 5) + ((q ^ sw) << 3);
        bfh[j] = *(const short8*)(&bb[8192 + rb]);
        bfl[j] = *(const short8*)(&bb[12288 + rb]);
      }
      __builtin_amdgcn_s_setprio(1);
#pragma unroll
      for (int i = 0; i < 2; ++i)
#pragma unroll
        for (int j = 0; j < 4; ++j) {
          acc[i][j] = __builtin_amdgcn_mfma_f32_16x16x32_bf16(afh[i], bfl[j], acc[i][j], 0, 0, 0);
          acc[i][j] = __builtin_amdgcn_mfma_f32_16x16x32_bf16(afl[i], bfh[j], acc[i][j], 0, 0, 0);
          acc[i][j] = __builtin_amdgcn_mfma_f32_16x16x32_bf16(afh[i], bfh[j], acc[i][j], 0, 0, 0);
        }
      __builtin_amdgcn_s_setprio(0);
      __builtin_amdgcn_sched_barrier(0);
      __builtin_amdgcn_s_barrier();          // readers done before buf re-staged
    }
#pragma unroll
    for (int i = 0; i < 2; ++i) {
#pragma unroll
      for (int rg = 0; rg < 4; ++rg) {
        int l = row0 + (wa << 5) + (i << 4) + (q << 2) + rg;
        float sc = inv0b[l];
#pragma unroll
        for (int j = 0; j < 4; ++j) {
          float v = acc[i][j][rg] * sc;
          if (v > bval[j]) { bval[j] = v; bidx[j] = l; }
        }
      }
    }
  }

  __syncthreads();                            // tiles dead; alias reduce buffers
  float* lval = (float*)smem;                 // 128 cols x 16 slots = 8 KB
  int*   lidx = (int*)((char*)smem + 8192);   // 8 KB
  int slot = (wa << 2) + q;
#pragma unroll
  for (int j = 0; j < 4; ++j) {
    int col = (wm << 6) + (j << 4) + cc;
    lval[col * 16 + slot] = bval[j];
    lidx[col * 16 + slot] = bidx[j];
  }
  __syncthreads();
  if (t < 128) {
    float bv = -1e30f; int bi = 0x7FFFFFFF;
    for (int s = 0; s < 16; ++s) {
      float v = lval[t * 16 + s]; int id = lidx[t * 16 + s];
      if (v > bv || (v == bv && id < bi)) { bv = v; bi = id; }
    }
    size_t o = (size_t)(((b << 3) + lt) << 12) + (mt << 7) + t;
    pval[o] = bv; pidx[o] = bi;
  }
}

// ---------------- K5: reduce partials -> S, argmax
__global__ __launch_bounds__(256) void reduce_kernel(const float* __restrict__ pval,
    const int* __restrict__ pidx, const float* __restrict__ inv1,
    float* __restrict__ S, int* __restrict__ arg)
{
  int tid = blockIdx.x * 256 + threadIdx.x;
  int b = tid >> 12, m = tid & 4095;
  float bv = -1e30f; int bi = 0x7FFFFFFF;
  for (int lt = 0; lt < 8; ++lt) {
    size_t o = (size_t)(((b << 3) + lt) << 12) + m;
    float v = pval[o]; int id = pidx[o];
    if (v > bv || (v == bv && id < bi)) { bv = v; bi = id; }
  }
  S[tid] = bv * inv1[tid];
  arg[tid] = ((unsigned)bi < 4096u) ? bi : 0;
}

// ---------------- K6: T = fold3(gather(f0_unfold, arg))/9 -> NHWC fp32
__global__ __launch_bounds__(256) void tgather_kernel(const float* __restrict__ f0,
    const int* __restrict__ arg, float* __restrict__ T)
{
  __shared__ int a3[192];
  int y = blockIdx.x, b = blockIdx.y, t = threadIdx.x;
  if (t < 192) {
    int r = t >> 6, xx = t & 63;
    int yy = y + r - 1;
    a3[t] = (yy >= 0 && yy < 64) ? arg[(b << 12) + (yy << 6) + xx] : 0;
  }
  __syncthreads();
  int c = t & 63, pg = t >> 6;
  for (int it = 0; it < 16; ++it) {
    int px = pg + (it << 2);
    float sum = 0.f;
#pragma unroll
    for (int ki = 0; ki < 3; ++ki) {
      int yn = y + 1 - ki;
      if (yn < 0 || yn >= 64) continue;
#pragma unroll
      for (int kj = 0; kj < 3; ++kj) {
        int xn = px + 1 - kj;
        if (xn < 0 || xn >= 64) continue;
        int p = a3[((2 - ki) << 6) + xn];
        int sy = (p >> 6) + ki - 1, sx = (p & 63) + kj - 1;
        if (sy >= 0 && sy < 64 && sx >= 0 && sx < 64)
          sum += f0[((((size_t)b << 12) + (sy << 6) + sx) << 6) + c];
      }
    }
    T[((((size_t)b << 12) + (y << 6) + px)) * 64 + c] = sum * (1.f / 9.f);
  }
}

// ---------------- K7: implicit-GEMM MFMA conv (unchanged R16).
template<int KS, int CINCH>
__global__ __launch_bounds__(256) void conv_mfma(const float* __restrict__ in0,
    const float* __restrict__ in1, const u16* __restrict__ whp, const u16* __restrict__ wlp,
    const float* __restrict__ bias, float* __restrict__ outp,
    const float* __restrict__ res, const float* __restrict__ smul, int dorelu, int dm)
{
  constexpr int P = KS / 2;
  constexpr int CIN = CINCH * 32;
  constexpr int NKH = CINCH / 2;              // # of 64-cin units
  constexpr int NIT = KS * KS * NKH;
  constexpr int AST = 72;                     // row stride in u16 (144 B, 16B-aligned)
  __shared__ __align__(16) u16 Ah[2][32 * AST], Al[2][32 * AST];
  __shared__ __align__(16) u16 Bh[2][64 * AST], Bl[2][64 * AST];
  int tile = blockIdx.x, b = blockIdx.y;      // y = tile>>1, px half = tile&1
  int t = threadIdx.x;
  int lane = t & 63, w = t >> 6;
  int wpx = w >> 1, wm = w & 1;
  int cc = lane & 15, q = lane >> 4;
  int ty = tile >> 1, txb = (tile & 1) << 5;
  const size_t abase = (size_t)b << 12;
  f32x4 acc[2];
  acc[0] = (f32x4){0.f, 0.f, 0.f, 0.f};
  acc[1] = (f32x4){0.f, 0.f, 0.f, 0.f};

  uint4 rg[8];                                // staging regs
  int arow = t >> 2, acs = t & 3;             // A mapping (t<128): 16-ch quarter
  int tb = t - 128;                           // B mapping (t>=128)
  int brow = tb >> 1, bhalf = tb & 1;         // 64 rows x 2 halves of 32 ch

  auto issue_loads = [&](int itn) {
    int tapn = (NKH == 1) ? itn : (itn >> 1);
    int kh   = (NKH == 1) ? 0 : (itn & 1);
    int ki = tapn / KS, kj = tapn - ki * KS;
    if (t < 128) {
#pragma unroll
      for (int k = 0; k < 8; ++k) rg[k] = make_uint4(0u, 0u, 0u, 0u);
      int iy = ty + ki - P;
      int ix = txb + arow + kj - P;
      if ((unsigned)iy < 64u && (unsigned)ix < 64u) {
        size_t base = (abase + (iy << 6) + ix) << 6;
        int cg = kh * 64 + acs * 16;
        if (dm) {
#pragma unroll
          for (int k = 0; k < 4; ++k) {
            rg[k]     = *(const uint4*)(in0 + base + cg + 4 * k);
            rg[4 + k] = *(const uint4*)(in1 + base + cg + 4 * k);
          }
        } else {
          const float* sp = (CINCH == 4 && kh == 1) ? (in1 + base + (cg - 64))
                                                    : (in0 + base + cg);
#pragma unroll
          for (int k = 0; k < 4; ++k) rg[k] = *(const uint4*)(sp + 4 * k);
        }
      }
    } else {
      size_t so = (size_t)(tapn * 64 + brow) * CIN + kh * 64 + bhalf * 32;
#pragma unroll
      for (int k = 0; k < 4; ++k) {
        rg[k]     = *(const uint4*)&whp[so + 8 * k];
        rg[4 + k] = *(const uint4*)&wlp[so + 8 * k];
      }
    }
  };

  auto write_lds = [&](int cur) {
    if (t < 128) {
      float v[16];
      if (dm) {
#pragma unroll
        for (int k = 0; k < 4; ++k)
#pragma unroll
          for (int e = 0; e < 4; ++e)
            v[k * 4 + e] = __uint_as_float((&rg[4 + k].x)[e]) - __uint_as_float((&rg[k].x)[e]);
      } else {
#pragma unroll
        for (int k = 0; k < 4; ++k)
#pragma unroll
          for (int e = 0; e < 4; ++e)
            v[k * 4 + e] = __uint_as_float((&rg[k].x)[e]);
      }
      uint4 uh0, ul0, uh1, ul1;
      bsplit2(v[0], v[1], uh0.x, ul0.x);
      bsplit2(v[2], v[3], uh0.y, ul0.y);
      bsplit2(v[4], v[5], uh0.z, ul0.z);
      bsplit2(v[6], v[7], uh0.w, ul0.w);
      bsplit2(v[8], v[9], uh1.x, ul1.x);
      bsplit2(v[10], v[11], uh1.y, ul1.y);
      bsplit2(v[12], v[13], uh1.z, ul1.z);
      bsplit2(v[14], v[15], uh1.w, ul1.w);
      int o = arow * AST + acs * 16;
      *(uint4*)&Ah[cur][o]     = uh0;
      *(uint4*)&Ah[cur][o + 8] = uh1;
      *(uint4*)&Al[cur][o]     = ul0;
      *(uint4*)&Al[cur][o + 8] = ul1;
    } else {
      int o = brow * AST + bhalf * 32;
#pragma unroll
      for (int k = 0; k < 4; ++k) {
        *(uint4*)&Bh[cur][o + 8 * k] = rg[k];
        *(uint4*)&Bl[cur][o + 8 * k] = rg[4 + k];
      }
    }
  };

  issue_loads(0);
  for (int it = 0; it < NIT; ++it) {
    int cur = it & 1;
    write_lds(cur);                            // consumes rg (vmcnt waits auto)
    if (it + 1 < NIT) issue_loads(it + 1);     // in flight across the barrier
    asm volatile("s_waitcnt lgkmcnt(0)" ::: "memory");
    __builtin_amdgcn_s_barrier();
    __builtin_amdgcn_sched_barrier(0);
    short8 afh[2], afl[2], bfh[2][2], bfl[2][2];
#pragma unroll
    for (int ks = 0; ks < 2; ++ks) {
      int ra = ((wpx << 4) + cc) * AST + ks * 32 + (q << 3);
      afh[ks] = *(const short8*)&Ah[cur][ra];
      afl[ks] = *(const short8*)&Al[cur][ra];
#pragma unroll
      for (int j = 0; j < 2; ++j) {
        int rb = ((wm << 5) + (j << 4) + cc) * AST + ks * 32 + (q << 3);
        bfh[j][ks] = *(const short8*)&Bh[cur][rb];
        bfl[j][ks] = *(const short8*)&Bl[cur][rb];
      }
    }
#pragma unroll
    for (int ks = 0; ks < 2; ++ks) {
      acc[0] = __builtin_amdgcn_mfma_f32_16x16x32_bf16(afh[ks], bfl[0][ks], acc[0], 0, 0, 0);
      acc[1] = __builtin_amdgcn_mfma_f32_16x16x32_bf16(afh[ks], bfl[1][ks], acc[1], 0, 0, 0);
      acc[0] = __builtin_amdgcn_mfma_f32_16x16x32_bf16(afl[ks], bfh[0][ks], acc[0], 0, 0, 0);
      acc[1] = __builtin_amdgcn_mfma_f32_16x16x32_bf16(afl[ks], bfh[1][ks], acc[1], 0, 0, 0);
      acc[0] = __builtin_amdgcn_mfma_f32_16x16x32_bf16(afh[ks], bfh[0][ks], acc[0], 0, 0, 0);
      acc[1] = __builtin_amdgcn_mfma_f32_16x16x32_bf16(afh[ks], bfh[1][ks], acc[1], 0, 0, 0);
    }
  }
#pragma unroll
  for (int rgi = 0; rgi < 4; ++rgi) {
    int p = (ty << 6) + txb + (wpx << 4) + (q << 2) + rgi;
#pragma unroll
    for (int j = 0; j < 2; ++j) {
      int cout = (wm << 5) + (j << 4) + cc;
      float v = acc[j][rgi] + bias[cout];
      if (dorelu) v = fmaxf(v, 0.f);
      size_t oi = ((abase + p) << 6) + cout;
      if (smul) v = res[oi] + v * smul[abase + p];
      else if (res) v += res[oi];
      outp[oi] = v;
    }
  }
}

extern "C" void kernel_launch(void* const* d_in, const int* in_sizes, int n_in,
                              void* d_out, int out_size, void* d_ws, size_t ws_size,
                              hipStream_t stream)
{
  (void)in_sizes; (void)n_in; (void)out_size; (void)ws_size;
  const float* c0     = (const float*)d_in[0];
  const float* f0     = (const float*)d_in[1];
  const float* c1     = (const float*)d_in[2];
  const float* head_w = (const float*)d_in[3];
  const float* head_b = (const float*)d_in[4];
  const float* rb_w1  = (const float*)d_in[5];
  const float* rb_b1  = (const float*)d_in[6];
  const float* rb_w2  = (const float*)d_in[7];
  const float* rb_b2  = (const float*)d_in[8];
  const float* tail_w = (const float*)d_in[9];
  const float* tail_b = (const float*)d_in[10];
  const float* sq_w   = (const float*)d_in[11];
  const float* sq_b   = (const float*)d_in[12];
  float* out = (float*)d_out;
  char* ws = (char*)d_ws;

  // ---- layout: 15,958,016 B total (unchanged) ----
  const size_t OFF_SS0  = 0;
  const size_t OFF_SS1  = 65536;
  const size_t OFF_INV0 = 131072;
  const size_t OFF_INV1 = 196608;
  const size_t OFF_S    = 262144;
  const size_t OFF_ARG  = 327680;
  const size_t OFF_PVAL = 393216;       // 512 KB
  const size_t OFF_PIDX = 917504;       // 512 KB
  const size_t OFF_WHH  = 1441792;      // head  hi 204800
  const size_t OFF_WHL  = 1646592;      // head  lo 204800
  const size_t OFF_W1H  = 1851392;      // rb1   hi 73728
  const size_t OFF_W1L  = 1925120;
  const size_t OFF_W2H  = 1998848;      // rb2   hi 73728
  const size_t OFF_W2L  = 2072576;
  const size_t OFF_WTH  = 2146304;      // tail  hi 204800
  const size_t OFF_WTL  = 2351104;
  const size_t OFF_WSH  = 2555904;      // sq    hi 409600
  const size_t OFF_WSL  = 2965504;
  const size_t OFF_P0H  = 3375104;
  const size_t OFF_P0L  = OFF_P0H + 2230272;   // 5,605,376
  const size_t OFF_P1H  = OFF_P0L + 2230272;   // 7,835,648
  const size_t OFF_P1L  = OFF_P1H + 2230272;   // 10,065,920 (end 12,296,192)
  const size_t OFF_SA   = 3375104;      // 4 MB: x1 -> T
  const size_t OFF_SB   = 7569408;      // 4 MB: hb -> dcf
  const size_t OFF_SC   = 11763712;     // 4 MB: xb

  float* ss0  = (float*)(ws + OFF_SS0);
  float* ss1  = (float*)(ws + OFF_SS1);
  float* inv0 = (float*)(ws + OFF_INV0);
  float* inv1 = (float*)(ws + OFF_INV1);
  float* Sbuf = (float*)(ws + OFF_S);
  int*   argb = (int*)(ws + OFF_ARG);
  float* pval = (float*)(ws + OFF_PVAL);
  int*   pidx = (int*)(ws + OFF_PIDX);
  u16* whh = (u16*)(ws + OFF_WHH); u16* whl = (u16*)(ws + OFF_WHL);
  u16* w1h = (u16*)(ws + OFF_W1H); u16* w1l = (u16*)(ws + OFF_W1L);
  u16* w2h = (u16*)(ws + OFF_W2H); u16* w2l = (u16*)(ws + OFF_W2L);
  u16* wth = (u16*)(ws + OFF_WTH); u16* wtl = (u16*)(ws + OFF_WTL);
  u16* wsh = (u16*)(ws + OFF_WSH); u16* wsl = (u16*)(ws + OFF_WSL);
  u16* p0h = (u16*)(ws + OFF_P0H); u16* p0l = (u16*)(ws + OFF_P0L);
  u16* p1h = (u16*)(ws + OFF_P1H); u16* p1l = (u16*)(ws + OFF_P1L);
  float* x1  = (float*)(ws + OFF_SA);
  float* Tb  = (float*)(ws + OFF_SA);
  float* hb  = (float*)(ws + OFF_SB);
  float* dcf = (float*)(ws + OFF_SB);
  float* xb  = (float*)(ws + OFF_SC);

  dim3 b256(256);
  split_pad_kernel<<<dim3(1089, BATCH), b256, 0, stream>>>(c0, c1, p0h, p0l, p1h, p1l, ss0, ss1);
  norm_kernel<<<dim3(64), b256, 0, stream>>>(ss0, ss1, inv0, inv1);
  wprep<<<dim3(400), b256, 0, stream>>>(head_w, whh, whl, 64, 25, 102400);
  wprep<<<dim3(144), b256, 0, stream>>>(rb_w1 + 110592, w1h, w1l, 64, 9, 36864);
  wprep<<<dim3(144), b256, 0, stream>>>(rb_w2 + 110592, w2h, w2l, 64, 9, 36864);
  wprep<<<dim3(400), b256, 0, stream>>>(tail_w, wth, wtl, 64, 25, 102400);
  wprep<<<dim3(800), b256, 0, stream>>>(sq_w, wsh, wsl, 128, 25, 204800);

  corr_mfma<<<dim3(32, 8, BATCH), dim3(512), 0, stream>>>(p0h, p0l, p1h, p1l, inv0, pval, pidx);
  reduce_kernel<<<dim3(64), b256, 0, stream>>>(pval, pidx, inv1, Sbuf, argb);

  // conv stack (only residual block 3 affects output); all NHWC.
  dim3 cgrid(128, BATCH);
  conv_mfma<5, 2><<<cgrid, b256, 0, stream>>>(c0, c1, whh, whl, head_b, x1, nullptr, nullptr, 0, 1);
  conv_mfma<3, 2><<<cgrid, b256, 0, stream>>>(x1, nullptr, w1h, w1l, rb_b1 + 192, hb, nullptr, nullptr, 1, 0);
  conv_mfma<3, 2><<<cgrid, b256, 0, stream>>>(hb, nullptr, w2h, w2l, rb_b2 + 192, xb, x1, nullptr, 0, 0);
  conv_mfma<5, 2><<<cgrid, b256, 0, stream>>>(xb, nullptr, wth, wtl, tail_b, dcf, x1, nullptr, 0, 0);

  tgather_kernel<<<dim3(64, BATCH), b256, 0, stream>>>(f0, argb, Tb);   // x1 dead after conv4
  // conv5 with fused final: out = dcf + conv*S, written directly to output (NLC==NHWC)
  conv_mfma<5, 4><<<cgrid, b256, 0, stream>>>(dcf, Tb, wsh, wsl, sq_b, out, dcf, Sbuf, 0, 0);
}